// Round 1
// baseline (4872.898 us; speedup 1.0000x reference)
//
#include <hip/hip_runtime.h>
#include <math.h>

typedef unsigned long long u64;
typedef unsigned int u32;

#define LVTOP 600
#define IMTOP 300
#define NIMG 2
#define NLVL 5
#define NCAND (NLVL*LVTOP)          // 3000
#define NWORD 47                    // ceil(3000/64)

__constant__ int d_HW[5]    = {60800,15200,3800,950,247};
__constant__ int d_LGOFF[5] = {0,364800,456000,478800,484500};
__constant__ int d_RGOFF[5] = {0,1459200,1824000,1915200,1938000};

__device__ __forceinline__ u32 okey(float f){
  u32 u = __float_as_uint(f);
  return (u & 0x80000000u) ? ~u : (u | 0x80000000u);
}

// ---------------- bitonic sorts (block-wide, LDS) ----------------
template<int NN, int NT>
__device__ void bitonic_desc64(u64* a, int tid){
  for (int k = 2; k <= NN; k <<= 1){
    for (int j = k >> 1; j > 0; j >>= 1){
      __syncthreads();
      for (int i = tid; i < NN; i += NT){
        int ixj = i ^ j;
        if (ixj > i){
          u64 x = a[i], y = a[ixj];
          bool up = ((i & k) == 0);
          if (up ? (x < y) : (x > y)){ a[i] = y; a[ixj] = x; }
        }
      }
    }
  }
  __syncthreads();
}

template<int NN, int NT>
__device__ void bitonic_asc32(u32* a, int tid){
  for (int k = 2; k <= NN; k <<= 1){
    for (int j = k >> 1; j > 0; j >>= 1){
      __syncthreads();
      for (int i = tid; i < NN; i += NT){
        int ixj = i ^ j;
        if (ixj > i){
          u32 x = a[i], y = a[ixj];
          bool up = ((i & k) == 0);
          if (up ? (x > y) : (x < y)){ a[i] = y; a[ixj] = x; }
        }
      }
    }
  }
  __syncthreads();
}

// ---------------- K1: fused conv3x3+relu + logit/reg heads ----------------
// block = 256 threads (thread t = output channel co), tile = 32 consecutive x
// in one row. h tile lives only in LDS (union with x-halo buffer).
__global__ __launch_bounds__(256) void conv_fused(
    const float* __restrict__ x,      // [2][256][H][W]
    const float* __restrict__ cw,     // [256][256][3][3]
    const float* __restrict__ cb,     // [256]
    const float* __restrict__ lw,     // [3][256]
    const float* __restrict__ lb,     // [3]
    const float* __restrict__ rw,     // [12][256]
    const float* __restrict__ rb,     // [12]
    float* __restrict__ lg,           // this level: [2][H*W*3]
    float* __restrict__ rg,           // this level: [2][H*W*12]
    int H, int W, int tilesX)
{
  __shared__ __align__(16) float sm[8448]; // xs chunk [64][3][36]=6912 / h [256][33]=8448
  int n  = blockIdx.y;
  int ty = blockIdx.x / tilesX;
  int x0 = (blockIdx.x - ty*tilesX) * 32;
  int t  = threadIdx.x;
  const float* xin = x + (size_t)n * 256 * H * W;

  float acc[32];
  #pragma unroll
  for (int p = 0; p < 32; p++) acc[p] = 0.0f;

  for (int cc = 0; cc < 4; cc++){            // ci chunks of 64
    __syncthreads();
    for (int e = t; e < 64*3*34; e += 256){
      int ci = e / 102; int rem = e - ci*102; int r = rem / 34; int c = rem - r*34;
      int gy = ty - 1 + r; int gx = x0 - 1 + c;
      float v = 0.0f;
      if (gy >= 0 && gy < H && gx >= 0 && gx < W)
        v = xin[(size_t)(cc*64 + ci) * H * W + (size_t)gy * W + gx];
      sm[(ci*3 + r)*36 + c] = v;
    }
    __syncthreads();
    const float* wp = cw + ((size_t)t * 256 + cc*64) * 9;
    for (int ci = 0; ci < 64; ci++){
      float wv[9];
      #pragma unroll
      for (int q = 0; q < 9; q++) wv[q] = wp[ci*9 + q];
      #pragma unroll
      for (int ky = 0; ky < 3; ky++){
        float xr[36];
        #pragma unroll
        for (int q = 0; q < 9; q++){
          float4 v4 = *(const float4*)&sm[(ci*3 + ky)*36 + q*4];
          xr[q*4+0] = v4.x; xr[q*4+1] = v4.y; xr[q*4+2] = v4.z; xr[q*4+3] = v4.w;
        }
        #pragma unroll
        for (int kx = 0; kx < 3; kx++){
          float wk = wv[ky*3 + kx];
          #pragma unroll
          for (int p = 0; p < 32; p++)
            acc[p] = fmaf(wk, xr[p + kx], acc[p]);
        }
      }
    }
  }
  __syncthreads();
  // write h to LDS, stride 33 to avoid bank conflicts
  float bias = cb[t];
  #pragma unroll
  for (int p = 0; p < 32; p++) sm[t*33 + p] = fmaxf(acc[p] + bias, 0.0f);
  __syncthreads();
  // heads: jobs (o in 0..14, pos in 0..31)
  int pos0 = t & 31;
  int o0 = t >> 5;                  // 0..7
  for (int o = o0; o < 15; o += 8){
    const float* wvp = (o < 3) ? (lw + o*256) : (rw + (o-3)*256);
    float s = (o < 3) ? lb[o] : rb[o-3];
    for (int co = 0; co < 256; co++)
      s = fmaf(sm[co*33 + pos0], wvp[co], s);
    int gx = x0 + pos0;
    if (gx < W){
      size_t pos = (size_t)ty * W + gx;
      if (o < 3) lg[(size_t)n*H*W*3  + pos*3  + o]     = s;
      else       rg[(size_t)n*H*W*12 + pos*12 + (o-3)] = s;
    }
  }
}

// ---------------- K2: exact per-level top-600 + decode + clip ----------------
__global__ __launch_bounds__(1024) void topk_decode(
    const float* __restrict__ lg, const float* __restrict__ rg,
    const float* __restrict__ pr0, const float* __restrict__ pr1,
    const float* __restrict__ pr2, const float* __restrict__ pr3,
    const float* __restrict__ pr4,
    const float* __restrict__ imsizes,
    float* __restrict__ cbox, float* __restrict__ cscore, u32* __restrict__ cvalid)
{
  __shared__ u32 hist[2048];
  __shared__ u64 sel[1024];
  __shared__ u32 eqbuf[1024];
  __shared__ u32 scal[8];
  int tid = threadIdx.x;
  int l = blockIdx.x / NIMG;
  int n = blockIdx.x - l*NIMG;
  int HW = d_HW[l];
  int N = HW * 3;
  const float* lgl = lg + d_LGOFF[l] + (size_t)n * N;

  // pass 1: bits [31:21]
  for (int i = tid; i < 2048; i += 1024) hist[i] = 0;
  __syncthreads();
  for (int i = tid; i < N; i += 1024) atomicAdd(&hist[okey(lgl[i]) >> 21], 1u);
  __syncthreads();
  if (tid == 0){
    u32 cum = 0; int b = 2047;
    for (; b > 0; b--){ if (cum + hist[b] >= LVTOP) break; cum += hist[b]; }
    scal[0] = (u32)b; scal[1] = cum;
  }
  __syncthreads();
  u32 B1 = scal[0], base1 = scal[1];

  // pass 2: bits [20:10] within B1
  for (int i = tid; i < 2048; i += 1024) hist[i] = 0;
  __syncthreads();
  for (int i = tid; i < N; i += 1024){
    u32 k = okey(lgl[i]);
    if ((k >> 21) == B1) atomicAdd(&hist[(k >> 10) & 0x7FFu], 1u);
  }
  __syncthreads();
  if (tid == 0){
    u32 need = LVTOP - base1;
    u32 cum = 0; int b = 2047;
    for (; b > 0; b--){ if (cum + hist[b] >= need) break; cum += hist[b]; }
    scal[2] = (u32)b; scal[3] = base1 + cum;
  }
  __syncthreads();
  u32 B2 = scal[2], base2 = scal[3];

  // pass 3: bits [9:0] within (B1,B2)
  for (int i = tid; i < 1024; i += 1024) hist[i] = 0;
  __syncthreads();
  u32 hi21 = (B1 << 11) | B2;
  for (int i = tid; i < N; i += 1024){
    u32 k = okey(lgl[i]);
    if ((k >> 10) == hi21) atomicAdd(&hist[k & 0x3FFu], 1u);
  }
  __syncthreads();
  if (tid == 0){
    u32 need = LVTOP - base2;
    u32 cum = 0; int b = 1023;
    for (; b > 0; b--){ if (cum + hist[b] >= need) break; cum += hist[b]; }
    scal[4] = (hi21 << 10) | (u32)b;   // exact threshold key T
    scal[5] = base2 + cum;             // count of keys > T  (< 600)
    scal[6] = 0; scal[7] = 0;
  }
  __syncthreads();
  u32 T = scal[4], nAbove = scal[5], needEq = LVTOP - scal[5];

  for (int i = tid; i < 1024; i += 1024) sel[i] = 0;
  __syncthreads();
  // collect
  for (int i = tid; i < N; i += 1024){
    u32 k = okey(lgl[i]);
    if (k > T){
      u32 p = atomicAdd(&scal[6], 1u);
      sel[p] = ((u64)k << 32) | (0xFFFFFFFFu - (u32)i);
    } else if (k == T){
      u32 p = atomicAdd(&scal[7], 1u);
      if (p < 1024) eqbuf[p] = (u32)i;
    }
  }
  __syncthreads();
  u32 cntE = scal[7];
  if (cntE > needEq){               // pick lowest-index ties (lax.top_k semantics)
    u32 m = cntE < 1024u ? cntE : 1024u;
    for (int i = tid; i < 1024; i += 1024) if ((u32)i >= m) eqbuf[i] = 0xFFFFFFFFu;
    __syncthreads();
    bitonic_asc32<1024,1024>(eqbuf, tid);
  }
  __syncthreads();
  if ((u32)tid < needEq)
    sel[nAbove + tid] = ((u64)T << 32) | (0xFFFFFFFFu - eqbuf[tid]);
  __syncthreads();
  bitonic_desc64<1024,1024>(sel, tid);   // (key desc, idx asc)

  // decode + clip + validity, in top-k order
  if (tid < LVTOP){
    u64 c = sel[tid];
    u32 i = 0xFFFFFFFFu - (u32)c;
    float val = lgl[i];
    float score = 1.0f / (1.0f + expf(-val));
    int pp = (int)i / 3, a = (int)i - pp*3;
    const float* pri;
    if (l == 0) pri = pr0; else if (l == 1) pri = pr1; else if (l == 2) pri = pr2;
    else if (l == 3) pri = pr3; else pri = pr4;
    pri += (size_t)i * 4;
    const float* rgp = rg + d_RGOFF[l] + ((size_t)n * HW + pp) * 12 + a * 4;
    float px0 = pri[0], py0 = pri[1], px1 = pri[2], py1 = pri[3];
    float pw = px1 - px0, ph = py1 - py0;
    float pcx = px0 + 0.5f*pw, pcy = py0 + 0.5f*ph;
    const float BC = (float)4.135166556742356;   // log(1000/16)
    float dx = rgp[0], dy = rgp[1];
    float dw = fminf(rgp[2], BC), dh = fminf(rgp[3], BC);
    float cx = dx*pw + pcx, cy = dy*ph + pcy;
    float bw = pw * expf(dw), bh = ph * expf(dh);
    float x1 = cx - 0.5f*bw, y1 = cy - 0.5f*bh;
    float x2 = cx + 0.5f*bw, y2 = cy + 0.5f*bh;
    float imh = imsizes[n*2+0], imw = imsizes[n*2+1];
    x1 = fminf(fmaxf(x1, 0.0f), imw);
    y1 = fminf(fmaxf(y1, 0.0f), imh);
    x2 = fminf(fmaxf(x2, 0.0f), imw);
    y2 = fminf(fmaxf(y2, 0.0f), imh);
    u32 valid = (score >= 0.0f) && ((x2 - x1) >= 1e-2f) && ((y2 - y1) >= 1e-2f);
    int ci = n*NCAND + l*LVTOP + tid;
    cbox[ci*4+0] = x1; cbox[ci*4+1] = y1; cbox[ci*4+2] = x2; cbox[ci*4+3] = y2;
    cscore[ci] = score; cvalid[ci] = valid;
  }
}

// ---------------- K3: per-image stable sort by score desc ----------------
__global__ __launch_bounds__(1024) void sort_cand(
    const float* __restrict__ cscore, const u32* __restrict__ cvalid,
    const float* __restrict__ cbox,
    float* __restrict__ sbox, float* __restrict__ sob,
    float* __restrict__ sarea, u32* __restrict__ svalid)
{
  __shared__ u64 a[4096];
  int tid = threadIdx.x, n = blockIdx.x;
  for (int i = tid; i < 4096; i += 1024){
    if (i < NCAND){
      int ci = n*NCAND + i;
      float s = cvalid[ci] ? cscore[ci] : -1.0f;   // ref: where(valid, obj, -1.0)
      a[i] = ((u64)okey(s) << 32) | (0xFFFFFFFFu - (u32)i);
    } else a[i] = 0;
  }
  bitonic_desc64<4096,1024>(a, tid);
  for (int r = tid; r < NCAND; r += 1024){
    u32 li = 0xFFFFFFFFu - (u32)a[r];
    int ci = n*NCAND + (int)li;
    float b0 = cbox[ci*4+0], b1 = cbox[ci*4+1], b2 = cbox[ci*4+2], b3 = cbox[ci*4+3];
    int lvl = (int)li / LVTOP;
    float off = (float)(n*10 + lvl) * 4096.0f;     // replicate batched_nms offset fp32
    int so = n*NCAND + r;
    sbox[so*4+0]=b0; sbox[so*4+1]=b1; sbox[so*4+2]=b2; sbox[so*4+3]=b3;
    float o0=b0+off, o1=b1+off, o2=b2+off, o3=b3+off;
    sob[so*4+0]=o0; sob[so*4+1]=o1; sob[so*4+2]=o2; sob[so*4+3]=o3;
    sarea[so] = (o2-o0)*(o3-o1);
    svalid[so] = cvalid[ci];
  }
}

// ---------------- K4: NMS suppression bitmask (bits j>i with IoU>0.7) -------
__global__ __launch_bounds__(256) void nms_mask(
    const float* __restrict__ sob, const float* __restrict__ sarea,
    const u32* __restrict__ svalid, u64* __restrict__ mask)
{
  __shared__ float sj[64*5];
  int tid = threadIdx.x;
  int i = blockIdx.x * 256 + tid;
  int n = blockIdx.y;
  int w0 = blockIdx.z * 12;
  int w1 = (w0 + 12 < NWORD) ? (w0 + 12) : NWORD;
  bool act = (i < NCAND) && (svalid[n*NCAND + i] != 0);
  float oi0=0, oi1=0, oi2=0, oi3=0, ai=0;
  if (act){
    int so = n*NCAND + i;
    oi0 = sob[so*4+0]; oi1 = sob[so*4+1]; oi2 = sob[so*4+2]; oi3 = sob[so*4+3];
    ai = sarea[so];
  }
  for (int w = w0; w < w1; w++){
    __syncthreads();
    if (tid < 64){
      int j = w*64 + tid;
      if (j < NCAND){
        int so = n*NCAND + j;
        sj[tid*5+0]=sob[so*4+0]; sj[tid*5+1]=sob[so*4+1];
        sj[tid*5+2]=sob[so*4+2]; sj[tid*5+3]=sob[so*4+3];
        sj[tid*5+4]=sarea[so];
      }
    }
    __syncthreads();
    if (act){
      u64 bits = 0;
      int jj0 = (i >= w*64) ? (i - w*64 + 1) : 0;
      int jjend = (NCAND - w*64 < 64) ? (NCAND - w*64) : 64;
      for (int jj = jj0; jj < jjend; jj++){
        float oj0=sj[jj*5+0], oj1=sj[jj*5+1], oj2=sj[jj*5+2], oj3=sj[jj*5+3], aj=sj[jj*5+4];
        float ltx = fmaxf(oi0, oj0), lty = fmaxf(oi1, oj1);
        float rbx = fminf(oi2, oj2), rby = fminf(oi3, oj3);
        float wx = fmaxf(rbx - ltx, 0.0f), wy = fmaxf(rby - lty, 0.0f);
        float inter = wx * wy;
        float iou = inter / ((ai + aj) - inter);
        if (iou > 0.7f) bits |= (1ull << jj);
      }
      mask[((size_t)(n*NCAND + i))*NWORD + w] = bits;
    }
  }
}

// ---------------- K5: serial greedy scan (1 wave / image), early-exit @300 --
__global__ __launch_bounds__(64) void nms_scan(
    const u64* __restrict__ mask, const u32* __restrict__ svalid,
    u32* __restrict__ klist, u32* __restrict__ kcount)
{
  int t = threadIdx.x, n = blockIdx.x;
  u64 vw = 0;
  for (int c = 0; c < NWORD; c++){
    int i = c*64 + t;
    int pred = (i < NCAND) && (svalid[n*NCAND + i] != 0);
    u64 b = __ballot(pred);
    if (t == c) vw = b;
  }
  u64 remv = 0;
  int cnt = 0;
  for (int i = 0; i < NCAND; i++){
    int wsel = i >> 6, bit = i & 63;
    u32 rl = (u32)remv, rh = (u32)(remv >> 32);
    u32 vl = (u32)vw,   vh = (u32)(vw >> 32);
    u64 cw = ((u64)__shfl(rh, wsel) << 32) | (u64)(u32)__shfl(rl, wsel);
    u64 vv = ((u64)__shfl(vh, wsel) << 32) | (u64)(u32)__shfl(vl, wsel);
    bool keep = ((vv >> bit) & 1ull) && !((cw >> bit) & 1ull);
    if (keep){
      u64 m = 0;
      if (t < NWORD) m = mask[((size_t)(n*NCAND + i))*NWORD + t];
      remv |= m;
      if (t == 0 && cnt < IMTOP) klist[n*IMTOP + cnt] = (u32)i;
      cnt++;
      if (cnt >= IMTOP) break;
    }
  }
  if (t == 0) kcount[n] = (u32)cnt;
}

// ---------------- K6: write output (boxes, imidx, valid) as float32 ---------
__global__ __launch_bounds__(128) void write_out(
    const float* __restrict__ sbox, const u32* __restrict__ klist,
    const u32* __restrict__ kcount, float* __restrict__ out)
{
  int n = blockIdx.x, tid = threadIdx.x;
  u32 kc = kcount[n];
  if (kc > IMTOP) kc = IMTOP;
  for (int j = tid; j < IMTOP; j += 128){
    int slot = n*IMTOP + j;
    float b0=0, b1=0, b2=0, b3=0, vo=0;
    if ((u32)j < kc){
      u32 r = klist[n*IMTOP + j];
      int so = n*NCAND + (int)r;
      b0 = sbox[so*4+0]; b1 = sbox[so*4+1]; b2 = sbox[so*4+2]; b3 = sbox[so*4+3];
      vo = 1.0f;
    }
    out[slot*4+0]=b0; out[slot*4+1]=b1; out[slot*4+2]=b2; out[slot*4+3]=b3;
    out[2400 + slot] = (float)n;   // imout
    out[3000 + slot] = vo;         // vout
  }
}

extern "C" void kernel_launch(void* const* d_in, const int* in_sizes, int n_in,
                              void* d_out, int out_size, void* d_ws, size_t ws_size,
                              hipStream_t stream)
{
  // setup_inputs() dict order: fmap0,priors0,fmap1,priors1,...,imsizes,conv_w,conv_b,log_w,log_b,reg_w,reg_b
  const float* fmap[5]   = {(const float*)d_in[0], (const float*)d_in[2], (const float*)d_in[4],
                            (const float*)d_in[6], (const float*)d_in[8]};
  const float* priors[5] = {(const float*)d_in[1], (const float*)d_in[3], (const float*)d_in[5],
                            (const float*)d_in[7], (const float*)d_in[9]};
  const float* imsz   = (const float*)d_in[10];
  const float* conv_w = (const float*)d_in[11];
  const float* conv_b = (const float*)d_in[12];
  const float* log_w  = (const float*)d_in[13];
  const float* log_b  = (const float*)d_in[14];
  const float* reg_w  = (const float*)d_in[15];
  const float* reg_b  = (const float*)d_in[16];

  static const int H[5] = {200,100,50,25,13};
  static const int W[5] = {304,152,76,38,19};
  static const int LGOFF[5] = {0,364800,456000,478800,484500};
  static const int RGOFF[5] = {0,1459200,1824000,1915200,1938000};

  float* ws     = (float*)d_ws;
  float* lg     = ws;                      // 485982 floats
  float* rg     = lg + 485982;             // 1943928 floats
  float* cscore = rg + 1943928;            // 6000
  float* cbox   = cscore + 6000;           // 24000
  u32*   cvalid = (u32*)(cbox + 24000);    // 6000
  float* sbox   = (float*)(cvalid + 6000); // 24000
  float* sob    = sbox + 24000;            // 24000
  float* sarea  = sob + 24000;             // 6000
  u32*   svalid = (u32*)(sarea + 6000);    // 6000
  u32*   klist  = svalid + 6000;           // 600
  u32*   kcnt   = klist + 600;             // 2
  u64*   mask   = (u64*)(kcnt + 2);        // 282000 u64  (offset is 8B-aligned)

  for (int l = 0; l < 5; l++){
    int tilesX = (W[l] + 31) / 32;
    dim3 grid(tilesX * H[l], NIMG);
    conv_fused<<<grid, 256, 0, stream>>>(fmap[l], conv_w, conv_b, log_w, log_b, reg_w, reg_b,
                                         lg + LGOFF[l], rg + RGOFF[l], H[l], W[l], tilesX);
  }
  topk_decode<<<NLVL*NIMG, 1024, 0, stream>>>(lg, rg,
      priors[0], priors[1], priors[2], priors[3], priors[4],
      imsz, cbox, cscore, cvalid);
  sort_cand<<<NIMG, 1024, 0, stream>>>(cscore, cvalid, cbox, sbox, sob, sarea, svalid);
  nms_mask<<<dim3(12, NIMG, 4), 256, 0, stream>>>(sob, sarea, svalid, mask);
  nms_scan<<<NIMG, 64, 0, stream>>>(mask, svalid, klist, kcnt);
  write_out<<<NIMG, 128, 0, stream>>>(sbox, klist, kcnt, (float*)d_out);
}

// Round 3
// 2226.448 us; speedup vs baseline: 2.1886x; 2.1886x over previous
//
#include <hip/hip_runtime.h>
#include <math.h>

typedef unsigned long long u64;
typedef unsigned int u32;
typedef unsigned short u16;
typedef _Float16 f16;
typedef __attribute__((ext_vector_type(8))) _Float16 f16x8;
typedef __attribute__((ext_vector_type(8))) unsigned short ushort8;
typedef __attribute__((ext_vector_type(4))) float f32x4;

#define LVTOP 600
#define IMTOP 300
#define NIMG 2
#define NLVL 5
#define NCAND (NLVL*LVTOP)          // 3000
#define NWORD 47                    // ceil(3000/64)

__constant__ int d_HW[5]    = {60800,15200,3800,950,247};
__constant__ int d_LGOFF[5] = {0,364800,456000,478800,484500};
__constant__ int d_RGOFF[5] = {0,1459200,1824000,1915200,1938000};

__device__ __forceinline__ u32 okey(float f){
  u32 u = __float_as_uint(f);
  return (u & 0x80000000u) ? ~u : (u | 0x80000000u);
}

// fp16 split-2: v = hi + lo exactly to 22 mantissa bits (residual ~2^-23|v|).
__device__ __forceinline__ void f16_split(float v, u16& hb, u16& lb){
  f16 h = (f16)v;
  float r = v - (float)h;          // exact (Sterbenz)
  f16 l = (f16)r;
  hb = __builtin_bit_cast(u16, h);
  lb = __builtin_bit_cast(u16, l);
}

// ---------------- bitonic sorts (block-wide, LDS) ----------------
template<int NN, int NT>
__device__ void bitonic_desc64(u64* a, int tid){
  for (int k = 2; k <= NN; k <<= 1){
    for (int j = k >> 1; j > 0; j >>= 1){
      __syncthreads();
      for (int i = tid; i < NN; i += NT){
        int ixj = i ^ j;
        if (ixj > i){
          u64 x = a[i], y = a[ixj];
          bool up = ((i & k) == 0);
          if (up ? (x < y) : (x > y)){ a[i] = y; a[ixj] = x; }
        }
      }
    }
  }
  __syncthreads();
}

template<int NN, int NT>
__device__ void bitonic_asc32(u32* a, int tid){
  for (int k = 2; k <= NN; k <<= 1){
    for (int j = k >> 1; j > 0; j >>= 1){
      __syncthreads();
      for (int i = tid; i < NN; i += NT){
        int ixj = i ^ j;
        if (ixj > i){
          u32 x = a[i], y = a[ixj];
          bool up = ((i & k) == 0);
          if (up ? (x > y) : (x < y)){ a[i] = y; a[ixj] = x; }
        }
      }
    }
  }
  __syncthreads();
}

// ---------------- K0: weight prep — split-f16, MFMA-fragment-linear --------
// wT layout: [tap 9][cc 8][ntg 16] blocks of 1024 u16: hi[lane 64][8] then lo.
//   value(tap,cc,ntg,lane,j) = W[ci = cc*32 + (lane>>4)*8 + j][co = ntg*16 + (lane&15)]
// whB layout: [ks 8] blocks of 1024 u16: hi[lane][8] then lo;
//   value = Whead[n = lane&15][k = ks*32 + (lane>>4)*8 + j]
__global__ __launch_bounds__(256) void wprep(
    const float* __restrict__ cw, const float* __restrict__ lw,
    const float* __restrict__ rw, u16* __restrict__ wT, u16* __restrict__ whB)
{
  int t = threadIdx.x;
  if (blockIdx.x < 72){
    int id = blockIdx.x*256 + t;            // (tap, co, cc)
    int cc = id & 7;
    int co = (id >> 3) & 255;
    int tap = id >> 11;
    int ntg = co >> 4;
    size_t base = (size_t)((tap*8 + cc)*16 + ntg) * 1024;
    #pragma unroll
    for (int ci = 0; ci < 32; ci++){
      float v = cw[(size_t)co*2304 + (size_t)(cc*32 + ci)*9 + tap];
      u16 hi, lo; f16_split(v, hi, lo);
      int q = ci >> 3, j = ci & 7;
      int lane = q*16 + (co & 15);
      wT[base + lane*8 + j] = hi;
      wT[base + 512 + lane*8 + j] = lo;
    }
  } else if (t < 128){
    int ks = t >> 4, nn = t & 15;
    for (int ci = 0; ci < 32; ci++){
      int k = ks*32 + ci;
      float v = 0.0f;
      if (nn < 3) v = lw[nn*256 + k];
      else if (nn < 15) v = rw[(nn-3)*256 + k];
      u16 hi, lo; f16_split(v, hi, lo);
      int q = ci >> 3, j = ci & 7;
      int lane = q*16 + nn;
      whB[ks*1024 + lane*8 + j] = hi;
      whB[ks*1024 + 512 + lane*8 + j] = lo;
    }
  }
}

// ---------------- K1: conv3x3+relu + heads, split-f16 MFMA ------------------
// Block: 64 x-positions in row ty, all 256 co. 4 waves as 2(m)x2(n):
// wave = 32M x 128N = 2 mt x 8 nt frags of 16x16x32_f16.
// A (x tile) from LDS split-f16; B (weights) direct global from wT.
// 3-term split: AhBh + AlBh + AhBl (error ~1.5e-7 rel, below fp32 accum noise).
__global__ __launch_bounds__(256, 2) void conv_mfma(
    const float* __restrict__ x,
    const u16* __restrict__ wT,
    const u16* __restrict__ whB,
    const float* __restrict__ cb,
    const float* __restrict__ lb,
    const float* __restrict__ rb,
    float* __restrict__ lg,
    float* __restrict__ rg,
    int H, int W, int tilesX)
{
  __shared__ __align__(16) u16 smem[33792];   // 66 KB: xs (32 KB) / hA (66 KB) union
  u16* xs_h = smem;                // [3][68][40], 66 x used (x0-1 .. x0+64)
  u16* xs_l = smem + 8160;
  u16* hA_h = smem;                // [64 pos][264 co]
  u16* hA_l = smem + 16896;

  const int t = threadIdx.x;
  const int n = blockIdx.y;
  const int ty = blockIdx.x / tilesX;
  const int x0 = (blockIdx.x - ty*tilesX) * 64;
  const int wave = t >> 6, lane = t & 63;
  const int wm = wave & 1, wn = wave >> 1;
  const int quad = lane >> 4, l15 = lane & 15;
  const int HWp = H * W;
  const float* xin = x + (size_t)n * 256 * HWp;

  f32x4 acc[2][8];
  #pragma unroll
  for (int a = 0; a < 2; a++)
    #pragma unroll
    for (int b = 0; b < 8; b++) acc[a][b] = (f32x4){0.f,0.f,0.f,0.f};

  for (int cc = 0; cc < 8; cc++){
    __syncthreads();
    // stage xs: 792 jobs of 8 ci at fixed (row r, x xi)
    #pragma unroll
    for (int it = 0; it < 4; it++){
      int G = t + it*256;
      if (G < 792){
        int ci8 = G & 3;
        int P = G >> 2;                  // 0..197
        int r = P / 66, xi = P - r*66;
        int gy = ty - 1 + r, gx = x0 - 1 + xi;
        bool inb = (gy >= 0) & (gy < H) & (gx >= 0) & (gx < W);
        const float* gp = xin + (size_t)(cc*32 + ci8*8) * HWp + (size_t)(gy < 0 ? 0 : gy) * W + (gx < 0 ? 0 : gx);
        ushort8 hv, lv;
        #pragma unroll
        for (int j = 0; j < 8; j++){
          float v = inb ? gp[(size_t)j * HWp] : 0.0f;
          u16 hb, lb2; f16_split(v, hb, lb2);
          hv[j] = hb; lv[j] = lb2;
        }
        int off = (r*68 + xi)*40 + ci8*8;
        *(ushort8*)&xs_h[off] = hv;
        *(ushort8*)&xs_l[off] = lv;
      }
    }
    __syncthreads();

    for (int ky = 0; ky < 3; ky++){
      #pragma unroll
      for (int kx = 0; kx < 3; kx++){
        f16x8 Ah0, Al0, Ah1, Al1;
        {
          int xi0 = wm*32 + l15 + kx;
          int o0 = (ky*68 + xi0)*40 + quad*8;
          Ah0 = *(const f16x8*)&xs_h[o0];
          Al0 = *(const f16x8*)&xs_l[o0];
          int o1 = o0 + 16*40;
          Ah1 = *(const f16x8*)&xs_h[o1];
          Al1 = *(const f16x8*)&xs_l[o1];
        }
        const int tap = ky*3 + kx;
        const u16* bt = wT + (size_t)((tap*8 + cc)*16 + wn*8) * 1024 + lane*8;
        #pragma unroll
        for (int nt = 0; nt < 8; nt++){
          f16x8 Bh = *(const f16x8*)(bt + nt*1024);
          f16x8 Bl = *(const f16x8*)(bt + nt*1024 + 512);
          acc[0][nt] = __builtin_amdgcn_mfma_f32_16x16x32_f16(Ah0, Bh, acc[0][nt], 0,0,0);
          acc[1][nt] = __builtin_amdgcn_mfma_f32_16x16x32_f16(Ah1, Bh, acc[1][nt], 0,0,0);
          acc[0][nt] = __builtin_amdgcn_mfma_f32_16x16x32_f16(Al0, Bh, acc[0][nt], 0,0,0);
          acc[1][nt] = __builtin_amdgcn_mfma_f32_16x16x32_f16(Al1, Bh, acc[1][nt], 0,0,0);
          acc[0][nt] = __builtin_amdgcn_mfma_f32_16x16x32_f16(Ah0, Bl, acc[0][nt], 0,0,0);
          acc[1][nt] = __builtin_amdgcn_mfma_f32_16x16x32_f16(Ah1, Bl, acc[1][nt], 0,0,0);
        }
      }
    }
  }
  __syncthreads();   // conv reads of xs done; reuse LDS for hA

  // bias + ReLU, convert h to split-f16 in LDS (A-layout for head MFMA)
  #pragma unroll
  for (int mt = 0; mt < 2; mt++){
    #pragma unroll
    for (int nt = 0; nt < 8; nt++){
      int co = wn*128 + nt*16 + l15;
      float bias = cb[co];
      #pragma unroll
      for (int r = 0; r < 4; r++){
        float h = fmaxf(acc[mt][nt][r] + bias, 0.0f);
        u16 hb, lb2; f16_split(h, hb, lb2);
        int pos = wm*32 + mt*16 + quad*4 + r;
        hA_h[pos*264 + co] = hb;
        hA_l[pos*264 + co] = lb2;
      }
    }
  }
  __syncthreads();

  // head MFMA: wave handles pos block wave*16; n = head (15 used of 16)
  f32x4 a2 = (f32x4){0.f,0.f,0.f,0.f};
  #pragma unroll
  for (int ks = 0; ks < 8; ks++){
    int ao = (wave*16 + l15)*264 + ks*32 + quad*8;
    f16x8 Ah = *(const f16x8*)&hA_h[ao];
    f16x8 Al = *(const f16x8*)&hA_l[ao];
    const u16* wb = whB + ks*1024 + lane*8;
    f16x8 Bh = *(const f16x8*)wb;
    f16x8 Bl = *(const f16x8*)(wb + 512);
    a2 = __builtin_amdgcn_mfma_f32_16x16x32_f16(Ah, Bh, a2, 0,0,0);
    a2 = __builtin_amdgcn_mfma_f32_16x16x32_f16(Al, Bh, a2, 0,0,0);
    a2 = __builtin_amdgcn_mfma_f32_16x16x32_f16(Ah, Bl, a2, 0,0,0);
  }
  {
    int o = l15;
    float bias = (o < 3) ? lb[o] : ((o < 15) ? rb[o-3] : 0.0f);
    #pragma unroll
    for (int r = 0; r < 4; r++){
      int pos = wave*16 + quad*4 + r;
      int gx = x0 + pos;
      if (gx < W && o < 15){
        float v = a2[r] + bias;
        size_t pp = (size_t)ty * W + gx;
        if (o < 3) lg[(size_t)n*HWp*3  + pp*3  + o]     = v;
        else       rg[(size_t)n*HWp*12 + pp*12 + (o-3)] = v;
      }
    }
  }
}

// ---------------- K2: exact per-level top-600 + decode + clip ----------------
__global__ __launch_bounds__(1024) void topk_decode(
    const float* __restrict__ lg, const float* __restrict__ rg,
    const float* __restrict__ pr0, const float* __restrict__ pr1,
    const float* __restrict__ pr2, const float* __restrict__ pr3,
    const float* __restrict__ pr4,
    const float* __restrict__ imsizes,
    float* __restrict__ cbox, float* __restrict__ cscore, u32* __restrict__ cvalid)
{
  __shared__ u32 hist[2048];
  __shared__ u64 sel[1024];
  __shared__ u32 eqbuf[1024];
  __shared__ u32 scal[8];
  int tid = threadIdx.x;
  int l = blockIdx.x / NIMG;
  int n = blockIdx.x - l*NIMG;
  int HW = d_HW[l];
  int N = HW * 3;
  const float* lgl = lg + d_LGOFF[l] + (size_t)n * N;

  // pass 1: bits [31:21]
  for (int i = tid; i < 2048; i += 1024) hist[i] = 0;
  __syncthreads();
  for (int i = tid; i < N; i += 1024) atomicAdd(&hist[okey(lgl[i]) >> 21], 1u);
  __syncthreads();
  if (tid == 0){
    u32 cum = 0; int b = 2047;
    for (; b > 0; b--){ if (cum + hist[b] >= LVTOP) break; cum += hist[b]; }
    scal[0] = (u32)b; scal[1] = cum;
  }
  __syncthreads();
  u32 B1 = scal[0], base1 = scal[1];

  // pass 2: bits [20:10] within B1
  for (int i = tid; i < 2048; i += 1024) hist[i] = 0;
  __syncthreads();
  for (int i = tid; i < N; i += 1024){
    u32 k = okey(lgl[i]);
    if ((k >> 21) == B1) atomicAdd(&hist[(k >> 10) & 0x7FFu], 1u);
  }
  __syncthreads();
  if (tid == 0){
    u32 need = LVTOP - base1;
    u32 cum = 0; int b = 2047;
    for (; b > 0; b--){ if (cum + hist[b] >= need) break; cum += hist[b]; }
    scal[2] = (u32)b; scal[3] = base1 + cum;
  }
  __syncthreads();
  u32 B2 = scal[2], base2 = scal[3];

  // pass 3: bits [9:0] within (B1,B2)
  for (int i = tid; i < 1024; i += 1024) hist[i] = 0;
  __syncthreads();
  u32 hi21 = (B1 << 11) | B2;
  for (int i = tid; i < N; i += 1024){
    u32 k = okey(lgl[i]);
    if ((k >> 10) == hi21) atomicAdd(&hist[k & 0x3FFu], 1u);
  }
  __syncthreads();
  if (tid == 0){
    u32 need = LVTOP - base2;
    u32 cum = 0; int b = 1023;
    for (; b > 0; b--){ if (cum + hist[b] >= need) break; cum += hist[b]; }
    scal[4] = (hi21 << 10) | (u32)b;   // exact threshold key T
    scal[5] = base2 + cum;             // count of keys > T  (< 600)
    scal[6] = 0; scal[7] = 0;
  }
  __syncthreads();
  u32 T = scal[4], nAbove = scal[5], needEq = LVTOP - scal[5];

  for (int i = tid; i < 1024; i += 1024) sel[i] = 0;
  __syncthreads();
  // collect
  for (int i = tid; i < N; i += 1024){
    u32 k = okey(lgl[i]);
    if (k > T){
      u32 p = atomicAdd(&scal[6], 1u);
      sel[p] = ((u64)k << 32) | (0xFFFFFFFFu - (u32)i);
    } else if (k == T){
      u32 p = atomicAdd(&scal[7], 1u);
      if (p < 1024) eqbuf[p] = (u32)i;
    }
  }
  __syncthreads();
  u32 cntE = scal[7];
  if (cntE > needEq){               // pick lowest-index ties (lax.top_k semantics)
    u32 m = cntE < 1024u ? cntE : 1024u;
    for (int i = tid; i < 1024; i += 1024) if ((u32)i >= m) eqbuf[i] = 0xFFFFFFFFu;
    __syncthreads();
    bitonic_asc32<1024,1024>(eqbuf, tid);
  }
  __syncthreads();
  if ((u32)tid < needEq)
    sel[nAbove + tid] = ((u64)T << 32) | (0xFFFFFFFFu - eqbuf[tid]);
  __syncthreads();
  bitonic_desc64<1024,1024>(sel, tid);   // (key desc, idx asc)

  // decode + clip + validity, in top-k order
  if (tid < LVTOP){
    u64 c = sel[tid];
    u32 i = 0xFFFFFFFFu - (u32)c;
    float val = lgl[i];
    float score = 1.0f / (1.0f + expf(-val));
    int pp = (int)i / 3, a = (int)i - pp*3;
    const float* pri;
    if (l == 0) pri = pr0; else if (l == 1) pri = pr1; else if (l == 2) pri = pr2;
    else if (l == 3) pri = pr3; else pri = pr4;
    pri += (size_t)i * 4;
    const float* rgp = rg + d_RGOFF[l] + ((size_t)n * HW + pp) * 12 + a * 4;
    float px0 = pri[0], py0 = pri[1], px1 = pri[2], py1 = pri[3];
    float pw = px1 - px0, ph = py1 - py0;
    float pcx = px0 + 0.5f*pw, pcy = py0 + 0.5f*ph;
    const float BC = (float)4.135166556742356;   // log(1000/16)
    float dx = rgp[0], dy = rgp[1];
    float dw = fminf(rgp[2], BC), dh = fminf(rgp[3], BC);
    float cx = dx*pw + pcx, cy = dy*ph + pcy;
    float bw = pw * expf(dw), bh = ph * expf(dh);
    float x1 = cx - 0.5f*bw, y1 = cy - 0.5f*bh;
    float x2 = cx + 0.5f*bw, y2 = cy + 0.5f*bh;
    float imh = imsizes[n*2+0], imw = imsizes[n*2+1];
    x1 = fminf(fmaxf(x1, 0.0f), imw);
    y1 = fminf(fmaxf(y1, 0.0f), imh);
    x2 = fminf(fmaxf(x2, 0.0f), imw);
    y2 = fminf(fmaxf(y2, 0.0f), imh);
    u32 valid = (score >= 0.0f) && ((x2 - x1) >= 1e-2f) && ((y2 - y1) >= 1e-2f);
    int ci = n*NCAND + l*LVTOP + tid;
    cbox[ci*4+0] = x1; cbox[ci*4+1] = y1; cbox[ci*4+2] = x2; cbox[ci*4+3] = y2;
    cscore[ci] = score; cvalid[ci] = valid;
  }
}

// ---------------- K3: per-image stable sort by score desc ----------------
__global__ __launch_bounds__(1024) void sort_cand(
    const float* __restrict__ cscore, const u32* __restrict__ cvalid,
    const float* __restrict__ cbox,
    float* __restrict__ sbox, float* __restrict__ sob,
    float* __restrict__ sarea, u32* __restrict__ svalid)
{
  __shared__ u64 a[4096];
  int tid = threadIdx.x, n = blockIdx.x;
  for (int i = tid; i < 4096; i += 1024){
    if (i < NCAND){
      int ci = n*NCAND + i;
      float s = cvalid[ci] ? cscore[ci] : -1.0f;   // ref: where(valid, obj, -1.0)
      a[i] = ((u64)okey(s) << 32) | (0xFFFFFFFFu - (u32)i);
    } else a[i] = 0;
  }
  bitonic_desc64<4096,1024>(a, tid);
  for (int r = tid; r < NCAND; r += 1024){
    u32 li = 0xFFFFFFFFu - (u32)a[r];
    int ci = n*NCAND + (int)li;
    float b0 = cbox[ci*4+0], b1 = cbox[ci*4+1], b2 = cbox[ci*4+2], b3 = cbox[ci*4+3];
    int lvl = (int)li / LVTOP;
    float off = (float)(n*10 + lvl) * 4096.0f;     // replicate batched_nms offset fp32
    int so = n*NCAND + r;
    sbox[so*4+0]=b0; sbox[so*4+1]=b1; sbox[so*4+2]=b2; sbox[so*4+3]=b3;
    float o0=b0+off, o1=b1+off, o2=b2+off, o3=b3+off;
    sob[so*4+0]=o0; sob[so*4+1]=o1; sob[so*4+2]=o2; sob[so*4+3]=o3;
    sarea[so] = (o2-o0)*(o3-o1);
    svalid[so] = cvalid[ci];
  }
}

// ---------------- K4: NMS suppression bitmask (bits j>i with IoU>0.7) -------
__global__ __launch_bounds__(256) void nms_mask(
    const float* __restrict__ sob, const float* __restrict__ sarea,
    const u32* __restrict__ svalid, u64* __restrict__ mask)
{
  __shared__ float sj[64*5];
  int tid = threadIdx.x;
  int i = blockIdx.x * 256 + tid;
  int n = blockIdx.y;
  int w0 = blockIdx.z * 12;
  int w1 = (w0 + 12 < NWORD) ? (w0 + 12) : NWORD;
  bool act = (i < NCAND) && (svalid[n*NCAND + i] != 0);
  float oi0=0, oi1=0, oi2=0, oi3=0, ai=0;
  if (act){
    int so = n*NCAND + i;
    oi0 = sob[so*4+0]; oi1 = sob[so*4+1]; oi2 = sob[so*4+2]; oi3 = sob[so*4+3];
    ai = sarea[so];
  }
  for (int w = w0; w < w1; w++){
    __syncthreads();
    if (tid < 64){
      int j = w*64 + tid;
      if (j < NCAND){
        int so = n*NCAND + j;
        sj[tid*5+0]=sob[so*4+0]; sj[tid*5+1]=sob[so*4+1];
        sj[tid*5+2]=sob[so*4+2]; sj[tid*5+3]=sob[so*4+3];
        sj[tid*5+4]=sarea[so];
      }
    }
    __syncthreads();
    if (act){
      u64 bits = 0;
      int jj0 = (i >= w*64) ? (i - w*64 + 1) : 0;
      int jjend = (NCAND - w*64 < 64) ? (NCAND - w*64) : 64;
      for (int jj = jj0; jj < jjend; jj++){
        float oj0=sj[jj*5+0], oj1=sj[jj*5+1], oj2=sj[jj*5+2], oj3=sj[jj*5+3], aj=sj[jj*5+4];
        float ltx = fmaxf(oi0, oj0), lty = fmaxf(oi1, oj1);
        float rbx = fminf(oi2, oj2), rby = fminf(oi3, oj3);
        float wx = fmaxf(rbx - ltx, 0.0f), wy = fmaxf(rby - lty, 0.0f);
        float inter = wx * wy;
        float iou = inter / ((ai + aj) - inter);
        if (iou > 0.7f) bits |= (1ull << jj);
      }
      mask[((size_t)(n*NCAND + i))*NWORD + w] = bits;
    }
  }
}

// ---------------- K5: serial greedy scan (1 wave / image), early-exit @300 --
__global__ __launch_bounds__(64) void nms_scan(
    const u64* __restrict__ mask, const u32* __restrict__ svalid,
    u32* __restrict__ klist, u32* __restrict__ kcount)
{
  int t = threadIdx.x, n = blockIdx.x;
  u64 vw = 0;
  for (int c = 0; c < NWORD; c++){
    int i = c*64 + t;
    int pred = (i < NCAND) && (svalid[n*NCAND + i] != 0);
    u64 b = __ballot(pred);
    if (t == c) vw = b;
  }
  u64 remv = 0;
  int cnt = 0;
  for (int i = 0; i < NCAND; i++){
    int wsel = i >> 6, bit = i & 63;
    u32 rl = (u32)remv, rh = (u32)(remv >> 32);
    u32 vl = (u32)vw,   vh = (u32)(vw >> 32);
    u64 cw = ((u64)__shfl(rh, wsel) << 32) | (u64)(u32)__shfl(rl, wsel);
    u64 vv = ((u64)__shfl(vh, wsel) << 32) | (u64)(u32)__shfl(vl, wsel);
    bool keep = ((vv >> bit) & 1ull) && !((cw >> bit) & 1ull);
    if (keep){
      u64 m = 0;
      if (t < NWORD) m = mask[((size_t)(n*NCAND + i))*NWORD + t];
      remv |= m;
      if (t == 0 && cnt < IMTOP) klist[n*IMTOP + cnt] = (u32)i;
      cnt++;
      if (cnt >= IMTOP) break;
    }
  }
  if (t == 0) kcount[n] = (u32)cnt;
}

// ---------------- K6: write output (boxes, imidx, valid) as float32 ---------
__global__ __launch_bounds__(128) void write_out(
    const float* __restrict__ sbox, const u32* __restrict__ klist,
    const u32* __restrict__ kcount, float* __restrict__ out)
{
  int n = blockIdx.x, tid = threadIdx.x;
  u32 kc = kcount[n];
  if (kc > IMTOP) kc = IMTOP;
  for (int j = tid; j < IMTOP; j += 128){
    int slot = n*IMTOP + j;
    float b0=0, b1=0, b2=0, b3=0, vo=0;
    if ((u32)j < kc){
      u32 r = klist[n*IMTOP + j];
      int so = n*NCAND + (int)r;
      b0 = sbox[so*4+0]; b1 = sbox[so*4+1]; b2 = sbox[so*4+2]; b3 = sbox[so*4+3];
      vo = 1.0f;
    }
    out[slot*4+0]=b0; out[slot*4+1]=b1; out[slot*4+2]=b2; out[slot*4+3]=b3;
    out[2400 + slot] = (float)n;   // imout
    out[3000 + slot] = vo;         // vout
  }
}

extern "C" void kernel_launch(void* const* d_in, const int* in_sizes, int n_in,
                              void* d_out, int out_size, void* d_ws, size_t ws_size,
                              hipStream_t stream)
{
  const float* fmap[5]   = {(const float*)d_in[0], (const float*)d_in[2], (const float*)d_in[4],
                            (const float*)d_in[6], (const float*)d_in[8]};
  const float* priors[5] = {(const float*)d_in[1], (const float*)d_in[3], (const float*)d_in[5],
                            (const float*)d_in[7], (const float*)d_in[9]};
  const float* imsz   = (const float*)d_in[10];
  const float* conv_w = (const float*)d_in[11];
  const float* conv_b = (const float*)d_in[12];
  const float* log_w  = (const float*)d_in[13];
  const float* log_b  = (const float*)d_in[14];
  const float* reg_w  = (const float*)d_in[15];
  const float* reg_b  = (const float*)d_in[16];

  static const int H[5] = {200,100,50,25,13};
  static const int W[5] = {304,152,76,38,19};
  static const int LGOFF[5] = {0,364800,456000,478800,484500};
  static const int RGOFF[5] = {0,1459200,1824000,1915200,1938000};

  float* ws     = (float*)d_ws;
  float* lg     = ws;                      // 485982 floats
  float* rg     = lg + 485982;             // 1943928 floats
  float* cscore = rg + 1943928;            // 6000
  float* cbox   = cscore + 6000;           // 24000
  u32*   cvalid = (u32*)(cbox + 24000);    // 6000
  float* sbox   = (float*)(cvalid + 6000); // 24000
  float* sob    = sbox + 24000;            // 24000
  float* sarea  = sob + 24000;             // 6000
  u32*   svalid = (u32*)(sarea + 6000);    // 6000
  u32*   klist  = svalid + 6000;           // 600
  u32*   kcnt   = klist + 600;             // 2
  u64*   mask   = (u64*)(kcnt + 2);        // 282000 u64, ends at byte 12362048
  u16*   wT     = (u16*)((char*)d_ws + 12362048);  // 2359296 B
  u16*   whB    = (u16*)((char*)d_ws + 14721344);  // 16384 B

  wprep<<<73, 256, 0, stream>>>(conv_w, log_w, reg_w, wT, whB);

  for (int l = 0; l < 5; l++){
    int tilesX = (W[l] + 63) / 64;
    dim3 grid(tilesX * H[l], NIMG);
    conv_mfma<<<grid, 256, 0, stream>>>(fmap[l], wT, whB, conv_b, log_b, reg_b,
                                        lg + LGOFF[l], rg + RGOFF[l], H[l], W[l], tilesX);
  }
  topk_decode<<<NLVL*NIMG, 1024, 0, stream>>>(lg, rg,
      priors[0], priors[1], priors[2], priors[3], priors[4],
      imsz, cbox, cscore, cvalid);
  sort_cand<<<NIMG, 1024, 0, stream>>>(cscore, cvalid, cbox, sbox, sob, sarea, svalid);
  nms_mask<<<dim3(12, NIMG, 4), 256, 0, stream>>>(sob, sarea, svalid, mask);
  nms_scan<<<NIMG, 64, 0, stream>>>(mask, svalid, klist, kcnt);
  write_out<<<NIMG, 128, 0, stream>>>(sbox, klist, kcnt, (float*)d_out);
}

// Round 4
// 1561.209 us; speedup vs baseline: 3.1212x; 1.4261x over previous
//
#include <hip/hip_runtime.h>
#include <math.h>

typedef unsigned long long u64;
typedef unsigned int u32;
typedef unsigned short u16;
typedef _Float16 f16;
typedef __attribute__((ext_vector_type(8))) _Float16 f16x8;
typedef __attribute__((ext_vector_type(8))) unsigned short ushort8;
typedef __attribute__((ext_vector_type(4))) float f32x4;

#define LVTOP 600
#define IMTOP 300
#define NIMG 2
#define NLVL 5
#define NCAND (NLVL*LVTOP)          // 3000
#define NWORD 47                    // ceil(3000/64)

__constant__ int d_HW[5]    = {60800,15200,3800,950,247};
__constant__ int d_LGOFF[5] = {0,364800,456000,478800,484500};
__constant__ int d_RGOFF[5] = {0,1459200,1824000,1915200,1938000};
__constant__ int d_H[5]  = {200,100,50,25,13};
__constant__ int d_W[5]  = {304,152,76,38,19};
__constant__ int d_TX[5] = {5,3,2,1,1};
// block bases: 0, 1000, 1300, 1400, 1425; total 1438

__device__ __forceinline__ u32 okey(float f){
  u32 u = __float_as_uint(f);
  return (u & 0x80000000u) ? ~u : (u | 0x80000000u);
}

// fp16 split-2: v = hi + lo exactly to 22 mantissa bits (residual ~2^-23|v|).
__device__ __forceinline__ void f16_split(float v, u16& hb, u16& lb){
  f16 h = (f16)v;
  float r = v - (float)h;          // exact (Sterbenz)
  f16 l = (f16)r;
  hb = __builtin_bit_cast(u16, h);
  lb = __builtin_bit_cast(u16, l);
}

// ---------------- bitonic sorts (block-wide, LDS) ----------------
template<int NN, int NT>
__device__ void bitonic_desc64(u64* a, int tid){
  for (int k = 2; k <= NN; k <<= 1){
    for (int j = k >> 1; j > 0; j >>= 1){
      __syncthreads();
      for (int i = tid; i < NN; i += NT){
        int ixj = i ^ j;
        if (ixj > i){
          u64 x = a[i], y = a[ixj];
          bool up = ((i & k) == 0);
          if (up ? (x < y) : (x > y)){ a[i] = y; a[ixj] = x; }
        }
      }
    }
  }
  __syncthreads();
}

template<int NN, int NT>
__device__ void bitonic_asc32(u32* a, int tid){
  for (int k = 2; k <= NN; k <<= 1){
    for (int j = k >> 1; j > 0; j >>= 1){
      __syncthreads();
      for (int i = tid; i < NN; i += NT){
        int ixj = i ^ j;
        if (ixj > i){
          u32 x = a[i], y = a[ixj];
          bool up = ((i & k) == 0);
          if (up ? (x > y) : (x < y)){ a[i] = y; a[ixj] = x; }
        }
      }
    }
  }
  __syncthreads();
}

// ---------------- K0: weight prep — split-f16, MFMA-fragment-linear --------
__global__ __launch_bounds__(256) void wprep(
    const float* __restrict__ cw, const float* __restrict__ lw,
    const float* __restrict__ rw, u16* __restrict__ wT, u16* __restrict__ whB)
{
  int t = threadIdx.x;
  if (blockIdx.x < 72){
    int id = blockIdx.x*256 + t;            // (tap, co, cc)
    int cc = id & 7;
    int co = (id >> 3) & 255;
    int tap = id >> 11;
    int ntg = co >> 4;
    size_t base = (size_t)((tap*8 + cc)*16 + ntg) * 1024;
    #pragma unroll
    for (int ci = 0; ci < 32; ci++){
      float v = cw[(size_t)co*2304 + (size_t)(cc*32 + ci)*9 + tap];
      u16 hi, lo; f16_split(v, hi, lo);
      int q = ci >> 3, j = ci & 7;
      int lane = q*16 + (co & 15);
      wT[base + lane*8 + j] = hi;
      wT[base + 512 + lane*8 + j] = lo;
    }
  } else if (t < 128){
    int ks = t >> 4, nn = t & 15;
    for (int ci = 0; ci < 32; ci++){
      int k = ks*32 + ci;
      float v = 0.0f;
      if (nn < 3) v = lw[nn*256 + k];
      else if (nn < 15) v = rw[(nn-3)*256 + k];
      u16 hi, lo; f16_split(v, hi, lo);
      int q = ci >> 3, j = ci & 7;
      int lane = q*16 + nn;
      whB[ks*1024 + lane*8 + j] = hi;
      whB[ks*1024 + 512 + lane*8 + j] = lo;
    }
  }
}

// ---------------- K1: all-level fused conv3x3+relu + heads, split-f16 MFMA --
// One dispatch for the whole pyramid; level decoded from blockIdx.x.
// LDS <= 34816 B -> 4 blocks/CU; head done in two K=128 halves.
__global__ __launch_bounds__(256, 4) void conv_mfma(
    const float* __restrict__ f0, const float* __restrict__ f1,
    const float* __restrict__ f2, const float* __restrict__ f3,
    const float* __restrict__ f4,
    const u16* __restrict__ wT,
    const u16* __restrict__ whB,
    const float* __restrict__ cb,
    const float* __restrict__ lb,
    const float* __restrict__ rb,
    float* __restrict__ lgb,
    float* __restrict__ rgb)
{
  __shared__ __align__(16) u16 smem[17408]; // 34816 B: xs (32640 B) / hA (34816 B)
  u16* xs_h = smem;                // [3][68][40], 66 x used
  u16* xs_l = smem + 8160;
  u16* hA_h = smem;                // [64 pos][136] (one 128-co half)
  u16* hA_l = smem + 8704;

  const int t = threadIdx.x;
  const int n = blockIdx.y;
  int bx = blockIdx.x;
  int l, rbk;
  if (bx < 1000){ l = 0; rbk = bx; }
  else if (bx < 1300){ l = 1; rbk = bx - 1000; }
  else if (bx < 1400){ l = 2; rbk = bx - 1300; }
  else if (bx < 1425){ l = 3; rbk = bx - 1400; }
  else { l = 4; rbk = bx - 1425; }
  const int H = d_H[l], W = d_W[l], tilesX = d_TX[l];
  const int ty = rbk / tilesX;
  const int x0 = (rbk - ty*tilesX) * 64;
  const float* fm = (l==0) ? f0 : (l==1) ? f1 : (l==2) ? f2 : (l==3) ? f3 : f4;
  float* lg = lgb + d_LGOFF[l];
  float* rg = rgb + d_RGOFF[l];

  const int wave = t >> 6, lane = t & 63;
  const int wm = wave & 1, wn = wave >> 1;
  const int quad = lane >> 4, l15 = lane & 15;
  const int HWp = H * W;
  const float* xin = fm + (size_t)n * 256 * HWp;

  f32x4 acc[2][8];
  #pragma unroll
  for (int a = 0; a < 2; a++)
    #pragma unroll
    for (int b = 0; b < 8; b++) acc[a][b] = (f32x4){0.f,0.f,0.f,0.f};

  for (int cc = 0; cc < 8; cc++){
    __syncthreads();
    // stage xs: 792 jobs of 8 ci at fixed (row r, x xi)
    #pragma unroll
    for (int it = 0; it < 4; it++){
      int G = t + it*256;
      if (G < 792){
        int ci8 = G & 3;
        int P = G >> 2;                  // 0..197
        int r = P / 66, xi = P - r*66;
        int gy = ty - 1 + r, gx = x0 - 1 + xi;
        bool inb = (gy >= 0) & (gy < H) & (gx >= 0) & (gx < W);
        const float* gp = xin + (size_t)(cc*32 + ci8*8) * HWp + (size_t)(gy < 0 ? 0 : gy) * W + (gx < 0 ? 0 : gx);
        ushort8 hv, lv;
        #pragma unroll
        for (int j = 0; j < 8; j++){
          float v = inb ? gp[(size_t)j * HWp] : 0.0f;
          u16 hb, lb2; f16_split(v, hb, lb2);
          hv[j] = hb; lv[j] = lb2;
        }
        int off = (r*68 + xi)*40 + ci8*8;
        *(ushort8*)&xs_h[off] = hv;
        *(ushort8*)&xs_l[off] = lv;
      }
    }
    __syncthreads();

    for (int ky = 0; ky < 3; ky++){
      #pragma unroll
      for (int kx = 0; kx < 3; kx++){
        f16x8 Ah0, Al0, Ah1, Al1;
        {
          int xi0 = wm*32 + l15 + kx;
          int o0 = (ky*68 + xi0)*40 + quad*8;
          Ah0 = *(const f16x8*)&xs_h[o0];
          Al0 = *(const f16x8*)&xs_l[o0];
          int o1 = o0 + 16*40;
          Ah1 = *(const f16x8*)&xs_h[o1];
          Al1 = *(const f16x8*)&xs_l[o1];
        }
        const int tap = ky*3 + kx;
        const u16* bt = wT + (size_t)((tap*8 + cc)*16 + wn*8) * 1024 + lane*8;
        #pragma unroll
        for (int nt = 0; nt < 8; nt++){
          f16x8 Bh = *(const f16x8*)(bt + nt*1024);
          f16x8 Bl = *(const f16x8*)(bt + nt*1024 + 512);
          acc[0][nt] = __builtin_amdgcn_mfma_f32_16x16x32_f16(Ah0, Bh, acc[0][nt], 0,0,0);
          acc[1][nt] = __builtin_amdgcn_mfma_f32_16x16x32_f16(Ah1, Bh, acc[1][nt], 0,0,0);
          acc[0][nt] = __builtin_amdgcn_mfma_f32_16x16x32_f16(Al0, Bh, acc[0][nt], 0,0,0);
          acc[1][nt] = __builtin_amdgcn_mfma_f32_16x16x32_f16(Al1, Bh, acc[1][nt], 0,0,0);
          acc[0][nt] = __builtin_amdgcn_mfma_f32_16x16x32_f16(Ah0, Bl, acc[0][nt], 0,0,0);
          acc[1][nt] = __builtin_amdgcn_mfma_f32_16x16x32_f16(Ah1, Bl, acc[1][nt], 0,0,0);
        }
      }
    }
  }
  __syncthreads();   // conv reads of xs done; reuse LDS for hA (K=128 halves)

  f32x4 a2 = (f32x4){0.f,0.f,0.f,0.f};
  #pragma unroll
  for (int half = 0; half < 2; half++){
    if (wn == half){
      #pragma unroll
      for (int mt = 0; mt < 2; mt++){
        #pragma unroll
        for (int nt = 0; nt < 8; nt++){
          int co = nt*16 + l15;            // local 0..127
          float bias = cb[half*128 + co];
          #pragma unroll
          for (int r = 0; r < 4; r++){
            float h = fmaxf(acc[mt][nt][r] + bias, 0.0f);
            u16 hb, lb2; f16_split(h, hb, lb2);
            int pos = wm*32 + mt*16 + quad*4 + r;
            hA_h[pos*136 + co] = hb;
            hA_l[pos*136 + co] = lb2;
          }
        }
      }
    }
    __syncthreads();
    #pragma unroll
    for (int ks2 = 0; ks2 < 4; ks2++){
      int ks = half*4 + ks2;
      int ao = (wave*16 + l15)*136 + ks2*32 + quad*8;
      f16x8 Ah = *(const f16x8*)&hA_h[ao];
      f16x8 Al = *(const f16x8*)&hA_l[ao];
      const u16* wb = whB + ks*1024 + lane*8;
      f16x8 Bh = *(const f16x8*)wb;
      f16x8 Bl = *(const f16x8*)(wb + 512);
      a2 = __builtin_amdgcn_mfma_f32_16x16x32_f16(Ah, Bh, a2, 0,0,0);
      a2 = __builtin_amdgcn_mfma_f32_16x16x32_f16(Al, Bh, a2, 0,0,0);
      a2 = __builtin_amdgcn_mfma_f32_16x16x32_f16(Ah, Bl, a2, 0,0,0);
    }
    __syncthreads();
  }

  {
    int o = l15;
    float bias = (o < 3) ? lb[o] : ((o < 15) ? rb[o-3] : 0.0f);
    #pragma unroll
    for (int r = 0; r < 4; r++){
      int pos = wave*16 + quad*4 + r;
      int gx = x0 + pos;
      if (gx < W && o < 15){
        float v = a2[r] + bias;
        size_t pp = (size_t)ty * W + gx;
        if (o < 3) lg[(size_t)n*HWp*3  + pp*3  + o]     = v;
        else       rg[(size_t)n*HWp*12 + pp*12 + (o-3)] = v;
      }
    }
  }
}

// ---------------- K2: exact per-level top-600 + decode + clip ----------------
__global__ __launch_bounds__(1024) void topk_decode(
    const float* __restrict__ lg, const float* __restrict__ rg,
    const float* __restrict__ pr0, const float* __restrict__ pr1,
    const float* __restrict__ pr2, const float* __restrict__ pr3,
    const float* __restrict__ pr4,
    const float* __restrict__ imsizes,
    float* __restrict__ cbox, float* __restrict__ cscore, u32* __restrict__ cvalid)
{
  __shared__ u32 hist[2048];
  __shared__ u64 sel[1024];
  __shared__ u32 eqbuf[1024];
  __shared__ u32 scal[8];
  int tid = threadIdx.x;
  int l = blockIdx.x / NIMG;
  int n = blockIdx.x - l*NIMG;
  int HW = d_HW[l];
  int N = HW * 3;
  const float* lgl = lg + d_LGOFF[l] + (size_t)n * N;

  // pass 1: bits [31:21]
  for (int i = tid; i < 2048; i += 1024) hist[i] = 0;
  __syncthreads();
  for (int i = tid; i < N; i += 1024) atomicAdd(&hist[okey(lgl[i]) >> 21], 1u);
  __syncthreads();
  if (tid == 0){
    u32 cum = 0; int b = 2047;
    for (; b > 0; b--){ if (cum + hist[b] >= LVTOP) break; cum += hist[b]; }
    scal[0] = (u32)b; scal[1] = cum;
  }
  __syncthreads();
  u32 B1 = scal[0], base1 = scal[1];

  // pass 2: bits [20:10] within B1
  for (int i = tid; i < 2048; i += 1024) hist[i] = 0;
  __syncthreads();
  for (int i = tid; i < N; i += 1024){
    u32 k = okey(lgl[i]);
    if ((k >> 21) == B1) atomicAdd(&hist[(k >> 10) & 0x7FFu], 1u);
  }
  __syncthreads();
  if (tid == 0){
    u32 need = LVTOP - base1;
    u32 cum = 0; int b = 2047;
    for (; b > 0; b--){ if (cum + hist[b] >= need) break; cum += hist[b]; }
    scal[2] = (u32)b; scal[3] = base1 + cum;
  }
  __syncthreads();
  u32 B2 = scal[2], base2 = scal[3];

  // pass 3: bits [9:0] within (B1,B2)
  for (int i = tid; i < 1024; i += 1024) hist[i] = 0;
  __syncthreads();
  u32 hi21 = (B1 << 11) | B2;
  for (int i = tid; i < N; i += 1024){
    u32 k = okey(lgl[i]);
    if ((k >> 10) == hi21) atomicAdd(&hist[k & 0x3FFu], 1u);
  }
  __syncthreads();
  if (tid == 0){
    u32 need = LVTOP - base2;
    u32 cum = 0; int b = 1023;
    for (; b > 0; b--){ if (cum + hist[b] >= need) break; cum += hist[b]; }
    scal[4] = (hi21 << 10) | (u32)b;   // exact threshold key T
    scal[5] = base2 + cum;             // count of keys > T  (< 600)
    scal[6] = 0; scal[7] = 0;
  }
  __syncthreads();
  u32 T = scal[4], nAbove = scal[5], needEq = LVTOP - scal[5];

  for (int i = tid; i < 1024; i += 1024) sel[i] = 0;
  __syncthreads();
  // collect
  for (int i = tid; i < N; i += 1024){
    u32 k = okey(lgl[i]);
    if (k > T){
      u32 p = atomicAdd(&scal[6], 1u);
      sel[p] = ((u64)k << 32) | (0xFFFFFFFFu - (u32)i);
    } else if (k == T){
      u32 p = atomicAdd(&scal[7], 1u);
      if (p < 1024) eqbuf[p] = (u32)i;
    }
  }
  __syncthreads();
  u32 cntE = scal[7];
  if (cntE > needEq){               // pick lowest-index ties (lax.top_k semantics)
    u32 m = cntE < 1024u ? cntE : 1024u;
    for (int i = tid; i < 1024; i += 1024) if ((u32)i >= m) eqbuf[i] = 0xFFFFFFFFu;
    __syncthreads();
    bitonic_asc32<1024,1024>(eqbuf, tid);
  }
  __syncthreads();
  if ((u32)tid < needEq)
    sel[nAbove + tid] = ((u64)T << 32) | (0xFFFFFFFFu - eqbuf[tid]);
  __syncthreads();
  bitonic_desc64<1024,1024>(sel, tid);   // (key desc, idx asc)

  // decode + clip + validity, in top-k order
  if (tid < LVTOP){
    u64 c = sel[tid];
    u32 i = 0xFFFFFFFFu - (u32)c;
    float val = lgl[i];
    float score = 1.0f / (1.0f + expf(-val));
    int pp = (int)i / 3, a = (int)i - pp*3;
    const float* pri;
    if (l == 0) pri = pr0; else if (l == 1) pri = pr1; else if (l == 2) pri = pr2;
    else if (l == 3) pri = pr3; else pri = pr4;
    pri += (size_t)i * 4;
    const float* rgp = rg + d_RGOFF[l] + ((size_t)n * HW + pp) * 12 + a * 4;
    float px0 = pri[0], py0 = pri[1], px1 = pri[2], py1 = pri[3];
    float pw = px1 - px0, ph = py1 - py0;
    float pcx = px0 + 0.5f*pw, pcy = py0 + 0.5f*ph;
    const float BC = (float)4.135166556742356;   // log(1000/16)
    float dx = rgp[0], dy = rgp[1];
    float dw = fminf(rgp[2], BC), dh = fminf(rgp[3], BC);
    float cx = dx*pw + pcx, cy = dy*ph + pcy;
    float bw = pw * expf(dw), bh = ph * expf(dh);
    float x1 = cx - 0.5f*bw, y1 = cy - 0.5f*bh;
    float x2 = cx + 0.5f*bw, y2 = cy + 0.5f*bh;
    float imh = imsizes[n*2+0], imw = imsizes[n*2+1];
    x1 = fminf(fmaxf(x1, 0.0f), imw);
    y1 = fminf(fmaxf(y1, 0.0f), imh);
    x2 = fminf(fmaxf(x2, 0.0f), imw);
    y2 = fminf(fmaxf(y2, 0.0f), imh);
    u32 valid = (score >= 0.0f) && ((x2 - x1) >= 1e-2f) && ((y2 - y1) >= 1e-2f);
    int ci = n*NCAND + l*LVTOP + tid;
    cbox[ci*4+0] = x1; cbox[ci*4+1] = y1; cbox[ci*4+2] = x2; cbox[ci*4+3] = y2;
    cscore[ci] = score; cvalid[ci] = valid;
  }
}

// ---------------- K3: per-image stable sort by score desc ----------------
__global__ __launch_bounds__(1024) void sort_cand(
    const float* __restrict__ cscore, const u32* __restrict__ cvalid,
    const float* __restrict__ cbox,
    float* __restrict__ sbox, float* __restrict__ sob,
    float* __restrict__ sarea, u32* __restrict__ svalid)
{
  __shared__ u64 a[4096];
  int tid = threadIdx.x, n = blockIdx.x;
  for (int i = tid; i < 4096; i += 1024){
    if (i < NCAND){
      int ci = n*NCAND + i;
      float s = cvalid[ci] ? cscore[ci] : -1.0f;   // ref: where(valid, obj, -1.0)
      a[i] = ((u64)okey(s) << 32) | (0xFFFFFFFFu - (u32)i);
    } else a[i] = 0;
  }
  bitonic_desc64<4096,1024>(a, tid);
  for (int r = tid; r < NCAND; r += 1024){
    u32 li = 0xFFFFFFFFu - (u32)a[r];
    int ci = n*NCAND + (int)li;
    float b0 = cbox[ci*4+0], b1 = cbox[ci*4+1], b2 = cbox[ci*4+2], b3 = cbox[ci*4+3];
    int lvl = (int)li / LVTOP;
    float off = (float)(n*10 + lvl) * 4096.0f;     // replicate batched_nms offset fp32
    int so = n*NCAND + r;
    sbox[so*4+0]=b0; sbox[so*4+1]=b1; sbox[so*4+2]=b2; sbox[so*4+3]=b3;
    float o0=b0+off, o1=b1+off, o2=b2+off, o3=b3+off;
    sob[so*4+0]=o0; sob[so*4+1]=o1; sob[so*4+2]=o2; sob[so*4+3]=o3;
    sarea[so] = (o2-o0)*(o3-o1);
    svalid[so] = cvalid[ci];
  }
}

// ---------------- K4: NMS suppression bitmask (bits j>i with IoU>0.7) -------
__global__ __launch_bounds__(256) void nms_mask(
    const float* __restrict__ sob, const float* __restrict__ sarea,
    const u32* __restrict__ svalid, u64* __restrict__ mask)
{
  __shared__ float sj[64*5];
  int tid = threadIdx.x;
  int i = blockIdx.x * 256 + tid;
  int n = blockIdx.y;
  int w0 = blockIdx.z * 12;
  int w1 = (w0 + 12 < NWORD) ? (w0 + 12) : NWORD;
  bool act = (i < NCAND) && (svalid[n*NCAND + i] != 0);
  float oi0=0, oi1=0, oi2=0, oi3=0, ai=0;
  if (act){
    int so = n*NCAND + i;
    oi0 = sob[so*4+0]; oi1 = sob[so*4+1]; oi2 = sob[so*4+2]; oi3 = sob[so*4+3];
    ai = sarea[so];
  }
  for (int w = w0; w < w1; w++){
    __syncthreads();
    if (tid < 64){
      int j = w*64 + tid;
      if (j < NCAND){
        int so = n*NCAND + j;
        sj[tid*5+0]=sob[so*4+0]; sj[tid*5+1]=sob[so*4+1];
        sj[tid*5+2]=sob[so*4+2]; sj[tid*5+3]=sob[so*4+3];
        sj[tid*5+4]=sarea[so];
      }
    }
    __syncthreads();
    if (act){
      u64 bits = 0;
      int jj0 = (i >= w*64) ? (i - w*64 + 1) : 0;
      int jjend = (NCAND - w*64 < 64) ? (NCAND - w*64) : 64;
      for (int jj = jj0; jj < jjend; jj++){
        float oj0=sj[jj*5+0], oj1=sj[jj*5+1], oj2=sj[jj*5+2], oj3=sj[jj*5+3], aj=sj[jj*5+4];
        float ltx = fmaxf(oi0, oj0), lty = fmaxf(oi1, oj1);
        float rbx = fminf(oi2, oj2), rby = fminf(oi3, oj3);
        float wx = fmaxf(rbx - ltx, 0.0f), wy = fmaxf(rby - lty, 0.0f);
        float inter = wx * wy;
        float iou = inter / ((ai + aj) - inter);
        if (iou > 0.7f) bits |= (1ull << jj);
      }
      mask[((size_t)(n*NCAND + i))*NWORD + w] = bits;
    }
  }
}

// ---------------- K5: serial greedy scan, 8-deep load pipeline --------------
__global__ __launch_bounds__(64) void nms_scan(
    const u64* __restrict__ mask, const u32* __restrict__ svalid,
    u32* __restrict__ klist, u32* __restrict__ kcount)
{
  int t = threadIdx.x, n = blockIdx.x;
  u64 vw = 0;
  for (int c = 0; c < NWORD; c++){
    int i = c*64 + t;
    int pred = (i < NCAND) && (svalid[n*NCAND + i] != 0);
    u64 b = __ballot(pred);
    if (t == c) vw = b;
  }
  u64 remv = 0;
  int cnt = 0;
  const u64* mrow = mask + (size_t)n * NCAND * NWORD;
  for (int g = 0; g < NCAND; g += 8){           // 3000 % 8 == 0
    u64 r[8];
    #pragma unroll
    for (int q = 0; q < 8; q++)
      r[q] = (t < NWORD) ? mrow[(size_t)(g+q)*NWORD + t] : 0;   // unconditional prefetch
    #pragma unroll
    for (int q = 0; q < 8; q++){
      int i = g + q;
      int wsel = i >> 6, bit = i & 63;
      u32 rl = (u32)remv, rh = (u32)(remv >> 32);
      u32 vl = (u32)vw,   vh = (u32)(vw >> 32);
      u64 cw = ((u64)__shfl(rh, wsel) << 32) | (u64)(u32)__shfl(rl, wsel);
      u64 vv = ((u64)__shfl(vh, wsel) << 32) | (u64)(u32)__shfl(vl, wsel);
      bool keep = ((vv >> bit) & 1ull) && !((cw >> bit) & 1ull);
      if (keep){
        remv |= r[q];                          // only valid rows get ORed (written rows)
        if (t == 0 && cnt < IMTOP) klist[n*IMTOP + cnt] = (u32)i;
        cnt++;
      }
    }
    if (cnt >= IMTOP) break;
  }
  if (t == 0) kcount[n] = (u32)(cnt > IMTOP ? IMTOP : cnt);
}

// ---------------- K6: write output (boxes, imidx, valid) as float32 ---------
__global__ __launch_bounds__(128) void write_out(
    const float* __restrict__ sbox, const u32* __restrict__ klist,
    const u32* __restrict__ kcount, float* __restrict__ out)
{
  int n = blockIdx.x, tid = threadIdx.x;
  u32 kc = kcount[n];
  if (kc > IMTOP) kc = IMTOP;
  for (int j = tid; j < IMTOP; j += 128){
    int slot = n*IMTOP + j;
    float b0=0, b1=0, b2=0, b3=0, vo=0;
    if ((u32)j < kc){
      u32 r = klist[n*IMTOP + j];
      int so = n*NCAND + (int)r;
      b0 = sbox[so*4+0]; b1 = sbox[so*4+1]; b2 = sbox[so*4+2]; b3 = sbox[so*4+3];
      vo = 1.0f;
    }
    out[slot*4+0]=b0; out[slot*4+1]=b1; out[slot*4+2]=b2; out[slot*4+3]=b3;
    out[2400 + slot] = (float)n;   // imout
    out[3000 + slot] = vo;         // vout
  }
}

extern "C" void kernel_launch(void* const* d_in, const int* in_sizes, int n_in,
                              void* d_out, int out_size, void* d_ws, size_t ws_size,
                              hipStream_t stream)
{
  const float* fmap[5]   = {(const float*)d_in[0], (const float*)d_in[2], (const float*)d_in[4],
                            (const float*)d_in[6], (const float*)d_in[8]};
  const float* priors[5] = {(const float*)d_in[1], (const float*)d_in[3], (const float*)d_in[5],
                            (const float*)d_in[7], (const float*)d_in[9]};
  const float* imsz   = (const float*)d_in[10];
  const float* conv_w = (const float*)d_in[11];
  const float* conv_b = (const float*)d_in[12];
  const float* log_w  = (const float*)d_in[13];
  const float* log_b  = (const float*)d_in[14];
  const float* reg_w  = (const float*)d_in[15];
  const float* reg_b  = (const float*)d_in[16];

  float* ws     = (float*)d_ws;
  float* lg     = ws;                      // 485982 floats
  float* rg     = lg + 485982;             // 1943928 floats
  float* cscore = rg + 1943928;            // 6000
  float* cbox   = cscore + 6000;           // 24000
  u32*   cvalid = (u32*)(cbox + 24000);    // 6000
  float* sbox   = (float*)(cvalid + 6000); // 24000
  float* sob    = sbox + 24000;            // 24000
  float* sarea  = sob + 24000;             // 6000
  u32*   svalid = (u32*)(sarea + 6000);    // 6000
  u32*   klist  = svalid + 6000;           // 600
  u32*   kcnt   = klist + 600;             // 2
  u64*   mask   = (u64*)(kcnt + 2);        // 282000 u64, ends at byte 12362048
  u16*   wT     = (u16*)((char*)d_ws + 12362048);  // 2359296 B
  u16*   whB    = (u16*)((char*)d_ws + 14721344);  // 16384 B

  wprep<<<73, 256, 0, stream>>>(conv_w, log_w, reg_w, wT, whB);

  conv_mfma<<<dim3(1438, NIMG), 256, 0, stream>>>(
      fmap[0], fmap[1], fmap[2], fmap[3], fmap[4],
      wT, whB, conv_b, log_b, reg_b, lg, rg);

  topk_decode<<<NLVL*NIMG, 1024, 0, stream>>>(lg, rg,
      priors[0], priors[1], priors[2], priors[3], priors[4],
      imsz, cbox, cscore, cvalid);
  sort_cand<<<NIMG, 1024, 0, stream>>>(cscore, cvalid, cbox, sbox, sob, sarea, svalid);
  nms_mask<<<dim3(12, NIMG, 4), 256, 0, stream>>>(sob, sarea, svalid, mask);
  nms_scan<<<NIMG, 64, 0, stream>>>(mask, svalid, klist, kcnt);
  write_out<<<NIMG, 128, 0, stream>>>(sbox, klist, kcnt, (float*)d_out);
}

// Round 5
// 1537.681 us; speedup vs baseline: 3.1690x; 1.0153x over previous
//
#include <hip/hip_runtime.h>
#include <math.h>

typedef unsigned long long u64;
typedef unsigned int u32;
typedef unsigned short u16;
typedef _Float16 f16;
typedef __attribute__((ext_vector_type(8))) _Float16 f16x8;
typedef __attribute__((ext_vector_type(8))) unsigned short ushort8;
typedef __attribute__((ext_vector_type(4))) float f32x4;

#define LVTOP 600
#define IMTOP 300
#define NIMG 2
#define NLVL 5
#define NCAND (NLVL*LVTOP)          // 3000

__constant__ int d_HW[5]    = {60800,15200,3800,950,247};
__constant__ int d_LGOFF[5] = {0,364800,456000,478800,484500};
__constant__ int d_RGOFF[5] = {0,1459200,1824000,1915200,1938000};
__constant__ int d_H[5]  = {200,100,50,25,13};
__constant__ int d_W[5]  = {304,152,76,38,19};
__constant__ int d_TX[5] = {5,3,2,1,1};
// xsplit u16 bases per level ([n][cg32][HW][8] chunks)
__constant__ long d_XB[5] = {0, 31129600, 38912000, 40857600, 41344000};
// chunk-count bases (XB/8)
__constant__ long d_CB[5] = {0, 3891200, 4864000, 5107200, 5168000};
#define NCHUNK 5183808
#define WS_NEED 178889200ull

__device__ __forceinline__ u32 okey(float f){
  u32 u = __float_as_uint(f);
  return (u & 0x80000000u) ? ~u : (u | 0x80000000u);
}

// fp16 split-2: v = hi + lo to 22 mantissa bits (residual ~2^-23|v|).
__device__ __forceinline__ void f16_split(float v, u16& hb, u16& lb){
  f16 h = (f16)v;
  float r = v - (float)h;          // exact (Sterbenz)
  f16 l = (f16)r;
  hb = __builtin_bit_cast(u16, h);
  lb = __builtin_bit_cast(u16, l);
}

__device__ __forceinline__ u64 shfl64(u64 v, int src){
  u32 lo = __shfl((u32)v, src);
  u32 hi = __shfl((u32)(v >> 32), src);
  return ((u64)hi << 32) | lo;
}

__device__ __forceinline__ void dma16(const u16* g, u16* l){
  __builtin_amdgcn_global_load_lds(
      (const __attribute__((address_space(1))) u32*)g,
      (__attribute__((address_space(3))) u32*)l, 16, 0, 0);
}

// ---------------- bitonic sorts (block-wide, LDS) ----------------
template<int NN, int NT>
__device__ void bitonic_desc64(u64* a, int tid){
  for (int k = 2; k <= NN; k <<= 1){
    for (int j = k >> 1; j > 0; j >>= 1){
      __syncthreads();
      for (int i = tid; i < NN; i += NT){
        int ixj = i ^ j;
        if (ixj > i){
          u64 x = a[i], y = a[ixj];
          bool up = ((i & k) == 0);
          if (up ? (x < y) : (x > y)){ a[i] = y; a[ixj] = x; }
        }
      }
    }
  }
  __syncthreads();
}

template<int NN, int NT>
__device__ void bitonic_asc32(u32* a, int tid){
  for (int k = 2; k <= NN; k <<= 1){
    for (int j = k >> 1; j > 0; j >>= 1){
      __syncthreads();
      for (int i = tid; i < NN; i += NT){
        int ixj = i ^ j;
        if (ixj > i){
          u32 x = a[i], y = a[ixj];
          bool up = ((i & k) == 0);
          if (up ? (x > y) : (x < y)){ a[i] = y; a[ixj] = x; }
        }
      }
    }
  }
  __syncthreads();
}

// parallel inclusive SUFFIX scan over s[0..NB), NB<=2048, 1024 threads
__device__ void suffix_scan(u32* s, int NB, int tid){
  for (int off = 1; off < NB; off <<= 1){
    u32 v0 = 0, v1 = 0;
    int i1 = tid + 1024;
    if (tid < NB) v0 = s[tid] + ((tid + off < NB) ? s[tid + off] : 0u);
    if (i1  < NB) v1 = s[i1]  + ((i1  + off < NB) ? s[i1  + off] : 0u);
    __syncthreads();
    if (tid < NB) s[tid] = v0;
    if (i1  < NB) s[i1]  = v1;
    __syncthreads();
  }
}

// ---------------- K0: weight prep — split-f16, MFMA-fragment-linear --------
__global__ __launch_bounds__(256) void wprep(
    const float* __restrict__ cw, const float* __restrict__ lw,
    const float* __restrict__ rw, u16* __restrict__ wT, u16* __restrict__ whB)
{
  int t = threadIdx.x;
  if (blockIdx.x < 72){
    int id = blockIdx.x*256 + t;            // (tap, co, cc)
    int cc = id & 7;
    int co = (id >> 3) & 255;
    int tap = id >> 11;
    int ntg = co >> 4;
    size_t base = (size_t)((tap*8 + cc)*16 + ntg) * 1024;
    #pragma unroll
    for (int ci = 0; ci < 32; ci++){
      float v = cw[(size_t)co*2304 + (size_t)(cc*32 + ci)*9 + tap];
      u16 hi, lo; f16_split(v, hi, lo);
      int q = ci >> 3, j = ci & 7;
      int lane = q*16 + (co & 15);
      wT[base + lane*8 + j] = hi;
      wT[base + 512 + lane*8 + j] = lo;
    }
  } else if (t < 128){
    int ks = t >> 4, nn = t & 15;
    for (int ci = 0; ci < 32; ci++){
      int k = ks*32 + ci;
      float v = 0.0f;
      if (nn < 3) v = lw[nn*256 + k];
      else if (nn < 15) v = rw[(nn-3)*256 + k];
      u16 hi, lo; f16_split(v, hi, lo);
      int q = ci >> 3, j = ci & 7;
      int lane = q*16 + nn;
      whB[ks*1024 + lane*8 + j] = hi;
      whB[ks*1024 + 512 + lane*8 + j] = lo;
    }
  }
}

// ---------------- K0b: pre-split fmaps into chunked split-f16 ---------------
// layout: chunk id = CB[l] + (n*32+cg)*HW + p ; 8 u16 per chunk = ci (cg*8+j)
__global__ __launch_bounds__(256) void xsplit(
    const float* __restrict__ f0, const float* __restrict__ f1,
    const float* __restrict__ f2, const float* __restrict__ f3,
    const float* __restrict__ f4,
    u16* __restrict__ xh, u16* __restrict__ xl, u16* __restrict__ zp)
{
  long id = (long)blockIdx.x*256 + threadIdx.x;
  if (blockIdx.x == 0 && threadIdx.x < 8) zp[threadIdx.x] = 0;   // 16B zero page
  if (id >= NCHUNK) return;
  int l = (id < d_CB[1]) ? 0 : (id < d_CB[2]) ? 1 : (id < d_CB[3]) ? 2 : (id < d_CB[4]) ? 3 : 4;
  long rem = id - d_CB[l];
  int HW = d_HW[l];
  int n = (int)(rem / (32*HW));
  int r2 = (int)(rem - (long)n*32*HW);
  int cg = r2 / HW;
  int p = r2 - cg*HW;
  const float* fm = (l==0)?f0:(l==1)?f1:(l==2)?f2:(l==3)?f3:f4;
  const float* gp = fm + ((size_t)(n*256 + cg*8))*HW + p;
  ushort8 hv, lv;
  #pragma unroll
  for (int j = 0; j < 8; j++){
    float v = gp[(size_t)j*HW];
    u16 hb, lb; f16_split(v, hb, lb);
    hv[j] = hb; lv[j] = lb;
  }
  *(ushort8*)&xh[id*8] = hv;
  *(ushort8*)&xl[id*8] = lv;
}

// ---------------- K1: all-level conv3x3+relu + heads, DMA dbuf MFMA ---------
// 64 x-pos/row per block, all 256 co; waves 2(m)x2(n), 16x16x32_f16 split-3.
// xs chunk g = ((cg*3+r)*68+xi), 16B each: DMA-contiguous AND 2-way-free b128.
__global__ __launch_bounds__(256, 3) void conv_mfma(
    const float* __restrict__ f0, const float* __restrict__ f1,
    const float* __restrict__ f2, const float* __restrict__ f3,
    const float* __restrict__ f4,
    const u16* __restrict__ xh, const u16* __restrict__ xl,
    const u16* __restrict__ zp,
    const u16* __restrict__ wT, const u16* __restrict__ whB,
    const float* __restrict__ cb, const float* __restrict__ lb,
    const float* __restrict__ rb,
    float* __restrict__ lgb, float* __restrict__ rgb, int use_dma)
{
  __shared__ __align__(16) u16 smem[26624];  // 53248 B: 2 x (xs_h 6656 + xs_l 6656)

  const int t = threadIdx.x;
  const int n = blockIdx.y;
  int bx = blockIdx.x;
  int l, rbk;
  if (bx < 1000){ l = 0; rbk = bx; }
  else if (bx < 1300){ l = 1; rbk = bx - 1000; }
  else if (bx < 1400){ l = 2; rbk = bx - 1300; }
  else if (bx < 1425){ l = 3; rbk = bx - 1400; }
  else { l = 4; rbk = bx - 1425; }
  const int H = d_H[l], W = d_W[l], tilesX = d_TX[l];
  const int ty = rbk / tilesX;
  const int x0 = (rbk - ty*tilesX) * 64;
  const float* fm = (l==0) ? f0 : (l==1) ? f1 : (l==2) ? f2 : (l==3) ? f3 : f4;

  const int wave = t >> 6, lane = t & 63;
  const int wm = wave & 1, wn = wave >> 1;
  const int quad = lane >> 4, l15 = lane & 15;
  const int HWp = H * W;
  const float* xin = fm + (size_t)n * 256 * HWp;

  f32x4 acc[2][8];
  #pragma unroll
  for (int a = 0; a < 2; a++)
    #pragma unroll
    for (int b = 0; b < 8; b++) acc[a][b] = (f32x4){0.f,0.f,0.f,0.f};

  // MFMA tap loop over one staged buffer
  auto compute_cc = [&](int cc, int bufo){
    #pragma unroll
    for (int ky = 0; ky < 3; ky++){
      #pragma unroll
      for (int kx = 0; kx < 3; kx++){
        int o0 = bufo + ((quad*3 + ky)*68 + (wm*32 + l15 + kx))*8;
        f16x8 Ah0 = *(const f16x8*)&smem[o0];
        f16x8 Al0 = *(const f16x8*)&smem[o0 + 6656];
        f16x8 Ah1 = *(const f16x8*)&smem[o0 + 128];
        f16x8 Al1 = *(const f16x8*)&smem[o0 + 6656 + 128];
        const u16* bt = wT + (size_t)((((ky*3+kx)*8 + cc)*16) + wn*8) * 1024 + lane*8;
        #pragma unroll
        for (int nt = 0; nt < 8; nt++){
          f16x8 Bh = *(const f16x8*)(bt + nt*1024);
          f16x8 Bl = *(const f16x8*)(bt + nt*1024 + 512);
          acc[0][nt] = __builtin_amdgcn_mfma_f32_16x16x32_f16(Ah0, Bh, acc[0][nt], 0,0,0);
          acc[1][nt] = __builtin_amdgcn_mfma_f32_16x16x32_f16(Ah1, Bh, acc[1][nt], 0,0,0);
          acc[0][nt] = __builtin_amdgcn_mfma_f32_16x16x32_f16(Al0, Bh, acc[0][nt], 0,0,0);
          acc[1][nt] = __builtin_amdgcn_mfma_f32_16x16x32_f16(Al1, Bh, acc[1][nt], 0,0,0);
          acc[0][nt] = __builtin_amdgcn_mfma_f32_16x16x32_f16(Ah0, Bl, acc[0][nt], 0,0,0);
          acc[1][nt] = __builtin_amdgcn_mfma_f32_16x16x32_f16(Ah1, Bl, acc[1][nt], 0,0,0);
        }
      }
    }
  };

  if (use_dma){
    // per-slot DMA descriptors: wave issues slots k = wave + 4s (13 instrs/array)
    const u16* ph[4]; const u16* pl[4]; u32 pstep[4]; int dsth[4]; int kv[4];
    #pragma unroll
    for (int s = 0; s < 4; s++){
      int k = wave + s*4;
      kv[s] = (k < 13);
      int g = k*64 + lane;               // chunk 0..831 (816 real + 16 pad)
      int gg = (g < 816) ? g : 0;
      int cg = gg / 204; int rem = gg - cg*204;
      int r = rem / 68;  int xi = rem - r*68;
      int gy = ty - 1 + r, gx = x0 - 1 + xi;
      bool inb = (g < 816) && (gy >= 0) && (gy < H) && (gx >= 0) && (gx < W);
      int gy2 = gy < 0 ? 0 : (gy >= H ? H-1 : gy);
      int gx2 = gx < 0 ? 0 : (gx >= W ? W-1 : gx);
      long off = d_XB[l] + (((long)(n*32 + cg))*HWp + (long)gy2*W + gx2)*8;
      ph[s] = inb ? (xh + off) : zp;
      pl[s] = inb ? (xl + off) : zp;
      pstep[s] = inb ? (u32)(32*HWp) : 0u;   // next cc: +4 channel-groups
      dsth[s] = k*512;                       // u16 offset (k*1024 B)
    }
    auto stage = [&](int bufo){
      #pragma unroll
      for (int s = 0; s < 4; s++){
        if (kv[s]){
          dma16(ph[s], &smem[bufo + dsth[s]]);
          dma16(pl[s], &smem[bufo + 6656 + dsth[s]]);
          ph[s] += pstep[s]; pl[s] += pstep[s];
        }
      }
    };
    stage(0);
    __syncthreads();                        // drains DMA for cc=0
    for (int cc = 0; cc < 8; cc++){
      if (cc < 7) stage(((cc+1)&1)*13312);  // in flight during compute
      compute_cc(cc, (cc&1)*13312);
      __syncthreads();                      // drains next DMA + protects buf reuse
    }
  } else {
    // fallback (small ws): f32 staging + in-register split, single buffer
    for (int cc = 0; cc < 8; cc++){
      __syncthreads();
      #pragma unroll
      for (int it = 0; it < 4; it++){
        int G = t + it*256;
        if (G < 816){
          int cg = G / 204; int rem = G - cg*204;
          int r = rem / 68; int xi = rem - r*68;
          int gy = ty - 1 + r, gx = x0 - 1 + xi;
          bool inb = (gy >= 0) & (gy < H) & (gx >= 0) & (gx < W);
          const float* gp = xin + (size_t)(cc*32 + cg*8) * HWp
                          + (size_t)(gy < 0 ? 0 : gy) * W + (gx < 0 ? 0 : gx);
          ushort8 hv, lv;
          #pragma unroll
          for (int j = 0; j < 8; j++){
            float v = inb ? gp[(size_t)j * HWp] : 0.0f;
            u16 hb, lb2; f16_split(v, hb, lb2);
            hv[j] = hb; lv[j] = lb2;
          }
          int off = ((cg*3 + r)*68 + xi)*8;
          *(ushort8*)&smem[off] = hv;
          *(ushort8*)&smem[6656 + off] = lv;
        }
      }
      __syncthreads();
      compute_cc(cc, 0);
    }
    __syncthreads();
  }

  // ---- heads: h -> split-f16 LDS (two K=128 halves), K=256 MFMA ----
  u16* hA_h = smem;                // [64 pos][136]
  u16* hA_l = smem + 8704;
  f32x4 a2 = (f32x4){0.f,0.f,0.f,0.f};
  #pragma unroll
  for (int half = 0; half < 2; half++){
    if (wn == half){
      #pragma unroll
      for (int mt = 0; mt < 2; mt++){
        #pragma unroll
        for (int nt = 0; nt < 8; nt++){
          int co = nt*16 + l15;            // local 0..127
          float bias = cb[half*128 + co];
          #pragma unroll
          for (int r = 0; r < 4; r++){
            float h = fmaxf(acc[mt][nt][r] + bias, 0.0f);
            u16 hb, lb2; f16_split(h, hb, lb2);
            int pos = wm*32 + mt*16 + quad*4 + r;
            hA_h[pos*136 + co] = hb;
            hA_l[pos*136 + co] = lb2;
          }
        }
      }
    }
    __syncthreads();
    #pragma unroll
    for (int ks2 = 0; ks2 < 4; ks2++){
      int ks = half*4 + ks2;
      int ao = (wave*16 + l15)*136 + ks2*32 + quad*8;
      f16x8 Ah = *(const f16x8*)&hA_h[ao];
      f16x8 Al = *(const f16x8*)&hA_l[ao];
      const u16* wb = whB + ks*1024 + lane*8;
      f16x8 Bh = *(const f16x8*)wb;
      f16x8 Bl = *(const f16x8*)(wb + 512);
      a2 = __builtin_amdgcn_mfma_f32_16x16x32_f16(Ah, Bh, a2, 0,0,0);
      a2 = __builtin_amdgcn_mfma_f32_16x16x32_f16(Al, Bh, a2, 0,0,0);
      a2 = __builtin_amdgcn_mfma_f32_16x16x32_f16(Ah, Bl, a2, 0,0,0);
    }
    __syncthreads();
  }

  // ---- coalesced epilogue through LDS ----
  float* sm_out = (float*)smem;            // [64 pos][16]
  {
    int o = l15;
    float bias = (o < 3) ? lb[o] : ((o < 15) ? rb[o-3] : 0.0f);
    #pragma unroll
    for (int r = 0; r < 4; r++){
      int pos = wave*16 + quad*4 + r;
      sm_out[pos*16 + o] = a2[r] + bias;
    }
  }
  __syncthreads();
  {
    int P = W - x0; if (P > 64) P = 64;
    size_t pbase = (size_t)ty * W + x0;
    float* lg = lgb + d_LGOFF[l] + (size_t)n*HWp*3  + pbase*3;
    float* rg = rgb + d_RGOFF[l] + (size_t)n*HWp*12 + pbase*12;
    for (int j = t; j < P*3; j += 256)  lg[j] = sm_out[(j/3)*16 + (j%3)];
    for (int j = t; j < P*12; j += 256) rg[j] = sm_out[(j/12)*16 + 3 + (j%12)];
  }
}

// ---------------- K2: exact per-level top-600 + decode + clip ----------------
__global__ __launch_bounds__(1024) void topk_decode(
    const float* __restrict__ lg, const float* __restrict__ rg,
    const float* __restrict__ pr0, const float* __restrict__ pr1,
    const float* __restrict__ pr2, const float* __restrict__ pr3,
    const float* __restrict__ pr4,
    const float* __restrict__ imsizes,
    float* __restrict__ cbox, float* __restrict__ cscore, u32* __restrict__ cvalid)
{
  __shared__ u32 hist[2048];
  __shared__ u32 sscan[2048];
  __shared__ u64 sel[1024];
  __shared__ u32 eqbuf[1024];
  __shared__ u32 scal[8];
  int tid = threadIdx.x;
  int l = blockIdx.x / NIMG;
  int n = blockIdx.x - l*NIMG;
  int HW = d_HW[l];
  int N = HW * 3;
  const float* lgl = lg + d_LGOFF[l] + (size_t)n * N;

  // pass 1: bits [31:21]
  for (int i = tid; i < 2048; i += 1024) hist[i] = 0;
  __syncthreads();
  for (int i = tid; i < N; i += 1024) atomicAdd(&hist[okey(lgl[i]) >> 21], 1u);
  __syncthreads();
  for (int i = tid; i < 2048; i += 1024) sscan[i] = hist[i];
  __syncthreads();
  suffix_scan(sscan, 2048, tid);
  if (tid < 2048){
    u32 Si = sscan[tid], Sn = (tid+1 < 2048) ? sscan[tid+1] : 0u;
    if (Si >= LVTOP && Sn < LVTOP){ scal[0] = (u32)tid; scal[1] = Si - hist[tid]; }
  }
  { int i2 = tid + 1024;
    u32 Si = sscan[i2], Sn = (i2+1 < 2048) ? sscan[i2+1] : 0u;
    if (Si >= LVTOP && Sn < LVTOP){ scal[0] = (u32)i2; scal[1] = Si - hist[i2]; } }
  __syncthreads();
  u32 B1 = scal[0], base1 = scal[1];

  // pass 2: bits [20:10] within B1
  for (int i = tid; i < 2048; i += 1024) hist[i] = 0;
  __syncthreads();
  for (int i = tid; i < N; i += 1024){
    u32 k = okey(lgl[i]);
    if ((k >> 21) == B1) atomicAdd(&hist[(k >> 10) & 0x7FFu], 1u);
  }
  __syncthreads();
  for (int i = tid; i < 2048; i += 1024) sscan[i] = hist[i];
  __syncthreads();
  suffix_scan(sscan, 2048, tid);
  {
    u32 need = LVTOP - base1;
    if (tid < 2048){
      u32 Si = sscan[tid], Sn = (tid+1 < 2048) ? sscan[tid+1] : 0u;
      if (Si >= need && Sn < need){ scal[2] = (u32)tid; scal[3] = base1 + Si - hist[tid]; }
    }
    int i2 = tid + 1024;
    u32 Si = sscan[i2], Sn = (i2+1 < 2048) ? sscan[i2+1] : 0u;
    if (Si >= need && Sn < need){ scal[2] = (u32)i2; scal[3] = base1 + Si - hist[i2]; }
  }
  __syncthreads();
  u32 B2 = scal[2], base2 = scal[3];

  // pass 3: bits [9:0] within (B1,B2)
  for (int i = tid; i < 1024; i += 1024) hist[i] = 0;
  __syncthreads();
  u32 hi21 = (B1 << 11) | B2;
  for (int i = tid; i < N; i += 1024){
    u32 k = okey(lgl[i]);
    if ((k >> 10) == hi21) atomicAdd(&hist[k & 0x3FFu], 1u);
  }
  __syncthreads();
  for (int i = tid; i < 1024; i += 1024) sscan[i] = hist[i];
  __syncthreads();
  suffix_scan(sscan, 1024, tid);
  {
    u32 need = LVTOP - base2;
    if (tid < 1024){
      u32 Si = sscan[tid], Sn = (tid+1 < 1024) ? sscan[tid+1] : 0u;
      if (Si >= need && Sn < need){
        scal[4] = (hi21 << 10) | (u32)tid;
        scal[5] = base2 + Si - hist[tid];
      }
    }
  }
  if (tid == 0){ scal[6] = 0; scal[7] = 0; }
  __syncthreads();
  u32 T = scal[4], nAbove = scal[5], needEq = LVTOP - scal[5];

  for (int i = tid; i < 1024; i += 1024) sel[i] = 0;
  __syncthreads();
  for (int i = tid; i < N; i += 1024){
    u32 k = okey(lgl[i]);
    if (k > T){
      u32 p = atomicAdd(&scal[6], 1u);
      sel[p] = ((u64)k << 32) | (0xFFFFFFFFu - (u32)i);
    } else if (k == T){
      u32 p = atomicAdd(&scal[7], 1u);
      if (p < 1024) eqbuf[p] = (u32)i;
    }
  }
  __syncthreads();
  u32 cntE = scal[7];
  if (cntE > needEq){               // lowest-index ties (lax.top_k semantics)
    u32 m = cntE < 1024u ? cntE : 1024u;
    for (int i = tid; i < 1024; i += 1024) if ((u32)i >= m) eqbuf[i] = 0xFFFFFFFFu;
    __syncthreads();
    bitonic_asc32<1024,1024>(eqbuf, tid);
  }
  __syncthreads();
  if ((u32)tid < needEq)
    sel[nAbove + tid] = ((u64)T << 32) | (0xFFFFFFFFu - eqbuf[tid]);
  __syncthreads();
  bitonic_desc64<1024,1024>(sel, tid);   // (key desc, idx asc)

  // decode + clip + validity
  if (tid < LVTOP){
    u64 c = sel[tid];
    u32 i = 0xFFFFFFFFu - (u32)c;
    float val = lgl[i];
    float score = 1.0f / (1.0f + expf(-val));
    int pp = (int)i / 3, a = (int)i - pp*3;
    const float* pri;
    if (l == 0) pri = pr0; else if (l == 1) pri = pr1; else if (l == 2) pri = pr2;
    else if (l == 3) pri = pr3; else pri = pr4;
    pri += (size_t)i * 4;
    const float* rgp = rg + d_RGOFF[l] + ((size_t)n * HW + pp) * 12 + a * 4;
    float px0 = pri[0], py0 = pri[1], px1 = pri[2], py1 = pri[3];
    float pw = px1 - px0, ph = py1 - py0;
    float pcx = px0 + 0.5f*pw, pcy = py0 + 0.5f*ph;
    const float BC = (float)4.135166556742356;   // log(1000/16)
    float dx = rgp[0], dy = rgp[1];
    float dw = fminf(rgp[2], BC), dh = fminf(rgp[3], BC);
    float cx = dx*pw + pcx, cy = dy*ph + pcy;
    float bw = pw * expf(dw), bh = ph * expf(dh);
    float x1 = cx - 0.5f*bw, y1 = cy - 0.5f*bh;
    float x2 = cx + 0.5f*bw, y2 = cy + 0.5f*bh;
    float imh = imsizes[n*2+0], imw = imsizes[n*2+1];
    x1 = fminf(fmaxf(x1, 0.0f), imw);
    y1 = fminf(fmaxf(y1, 0.0f), imh);
    x2 = fminf(fmaxf(x2, 0.0f), imw);
    y2 = fminf(fmaxf(y2, 0.0f), imh);
    u32 valid = (score >= 0.0f) && ((x2 - x1) >= 1e-2f) && ((y2 - y1) >= 1e-2f);
    int ci = n*NCAND + l*LVTOP + tid;
    cbox[ci*4+0] = x1; cbox[ci*4+1] = y1; cbox[ci*4+2] = x2; cbox[ci*4+3] = y2;
    cscore[ci] = score; cvalid[ci] = valid;
  }
}

// ---------------- K3: per-image stable sort + per-level rank lists ----------
__global__ __launch_bounds__(1024) void sort_cand(
    const float* __restrict__ cscore, const u32* __restrict__ cvalid,
    const float* __restrict__ cbox,
    float* __restrict__ sbox, float* __restrict__ sob,
    float* __restrict__ sarea, u32* __restrict__ svalid,
    u32* __restrict__ rlist, u32* __restrict__ kflag)
{
  __shared__ u64 a[4096];
  int tid = threadIdx.x, n = blockIdx.x;
  for (int i = tid; i < 4096; i += 1024){
    if (i < NCAND){
      int ci = n*NCAND + i;
      float s = cvalid[ci] ? cscore[ci] : -1.0f;   // ref: where(valid, obj, -1)
      a[i] = ((u64)okey(s) << 32) | (0xFFFFFFFFu - (u32)i);
    } else a[i] = 0;
  }
  bitonic_desc64<4096,1024>(a, tid);
  int mylvl[3];
  #pragma unroll
  for (int q = 0; q < 3; q++){
    int r = tid + q*1024;
    mylvl[q] = 0;
    if (r < NCAND){
      u32 li = 0xFFFFFFFFu - (u32)a[r];
      int ci = n*NCAND + (int)li;
      float b0 = cbox[ci*4+0], b1 = cbox[ci*4+1], b2 = cbox[ci*4+2], b3 = cbox[ci*4+3];
      int lvl = (int)li / LVTOP;
      mylvl[q] = lvl;
      float off = (float)(n*10 + lvl) * 4096.0f;   // fp32 batched_nms offset
      int so = n*NCAND + r;
      sbox[so*4+0]=b0; sbox[so*4+1]=b1; sbox[so*4+2]=b2; sbox[so*4+3]=b3;
      float o0=b0+off, o1=b1+off, o2=b2+off, o3=b3+off;
      sob[so*4+0]=o0; sob[so*4+1]=o1; sob[so*4+2]=o2; sob[so*4+3]=o3;
      sarea[so] = (o2-o0)*(o3-o1);
      svalid[so] = cvalid[ci];
    }
  }
  __syncthreads();
  // per-level stable position via one u64 multi-field inclusive scan
  #pragma unroll
  for (int q = 0; q < 3; q++){
    int r = tid + q*1024;
    a[r] = (r < NCAND) ? (1ull << (12*mylvl[q])) : 0ull;
  }
  a[tid + 3072] = 0ull;
  __syncthreads();
  for (int off = 1; off < 4096; off <<= 1){
    u64 v[4];
    #pragma unroll
    for (int q = 0; q < 4; q++){
      int i = tid + q*1024;
      v[q] = a[i] + ((i >= off) ? a[i-off] : 0ull);
    }
    __syncthreads();
    #pragma unroll
    for (int q = 0; q < 4; q++) a[tid + q*1024] = v[q];
    __syncthreads();
  }
  #pragma unroll
  for (int q = 0; q < 3; q++){
    int r = tid + q*1024;
    if (r < NCAND){
      int lv = mylvl[q];
      int pos = (int)((a[r] >> (12*lv)) & 0xFFFull) - 1;
      rlist[(n*NLVL + lv)*LVTOP + pos] = (u32)r;
      kflag[n*NCAND + r] = 0u;
    }
  }
}

// ---------------- K4: per-level NMS masks (600x600, 10 words/row) -----------
__global__ __launch_bounds__(256) void nms_mask_l(
    const float* __restrict__ sob, const float* __restrict__ sarea,
    const u32* __restrict__ svalid, const u32* __restrict__ rlist,
    u64* __restrict__ pmask)
{
  __shared__ float sj[64*5];
  int tid = threadIdx.x;
  int nl = blockIdx.y;              // n*5 + l
  int n = nl / NLVL;
  int i = blockIdx.x*256 + tid;     // level-local index
  bool act = false;
  float oi0=0, oi1=0, oi2=0, oi3=0, ai=0;
  if (i < LVTOP){
    int so = n*NCAND + (int)rlist[nl*LVTOP + i];
    act = svalid[so] != 0;
    oi0 = sob[so*4+0]; oi1 = sob[so*4+1]; oi2 = sob[so*4+2]; oi3 = sob[so*4+3];
    ai = sarea[so];
  }
  for (int w = 0; w < 10; w++){
    __syncthreads();
    if (tid < 64){
      int j = w*64 + tid;
      if (j < LVTOP){
        int so = n*NCAND + (int)rlist[nl*LVTOP + j];
        sj[tid*5+0]=sob[so*4+0]; sj[tid*5+1]=sob[so*4+1];
        sj[tid*5+2]=sob[so*4+2]; sj[tid*5+3]=sob[so*4+3];
        sj[tid*5+4]=sarea[so];
      }
    }
    __syncthreads();
    if (act){
      u64 bits = 0;
      int jj0 = (i >= w*64) ? (i - w*64 + 1) : 0;
      int jjend = (LVTOP - w*64 < 64) ? (LVTOP - w*64) : 64;
      for (int jj = jj0; jj < jjend; jj++){
        float oj0=sj[jj*5+0], oj1=sj[jj*5+1], oj2=sj[jj*5+2], oj3=sj[jj*5+3], aj=sj[jj*5+4];
        float ltx = fmaxf(oi0, oj0), lty = fmaxf(oi1, oj1);
        float rbx = fminf(oi2, oj2), rby = fminf(oi3, oj3);
        float wx = fmaxf(rbx - ltx, 0.0f), wy = fmaxf(rby - lty, 0.0f);
        float inter = wx * wy;
        float iou = inter / ((ai + aj) - inter);
        if (iou > 0.7f) bits |= (1ull << jj);
      }
      pmask[((size_t)(nl*LVTOP + i))*10 + w] = bits;
    }
  }
}

// ---------------- K5: 10 parallel word-skip greedy scans --------------------
__global__ __launch_bounds__(64) void nms_scan_l(
    const u64* __restrict__ pmask, const u32* __restrict__ svalid,
    const u32* __restrict__ rlist, u32* __restrict__ kflag)
{
  int t = threadIdx.x, nl = blockIdx.x, n = nl / NLVL;
  u64 vw = 0, remv = 0;
  for (int c = 0; c < 10; c++){
    int i = c*64 + t;
    int pred = 0;
    if (i < LVTOP) pred = svalid[n*NCAND + (int)rlist[nl*LVTOP + i]] != 0;
    u64 b = __ballot(pred);
    if (t == c) vw = b;
  }
  for (int w = 0; w < 10; w++){
    u64 act = shfl64(vw, w) & ~shfl64(remv, w);
    while (act){
      int bpos = __builtin_ctzll(act);
      int i = w*64 + bpos;
      if (t == 0) kflag[n*NCAND + (int)rlist[nl*LVTOP + i]] = 1u;
      u64 m = (t < 10) ? pmask[((size_t)(nl*LVTOP + i))*10 + t] : 0ull;
      remv |= m;
      act &= ~(1ull << bpos);
      act &= ~shfl64(m, w);
    }
  }
}

// ---------------- K6: prefix-sum cap-300 merge + output ---------------------
__global__ __launch_bounds__(1024) void merge_out(
    const u32* __restrict__ kflag, const float* __restrict__ sbox,
    float* __restrict__ out)
{
  __shared__ u32 ps[4096];
  int tid = threadIdx.x, n = blockIdx.x;
  u32 f[4];
  #pragma unroll
  for (int q = 0; q < 4; q++){
    int i = tid + q*1024;
    f[q] = (i < NCAND) ? kflag[n*NCAND + i] : 0u;
    ps[i] = f[q];
  }
  __syncthreads();
  for (int off = 1; off < 4096; off <<= 1){
    u32 v[4];
    #pragma unroll
    for (int q = 0; q < 4; q++){
      int i = tid + q*1024;
      v[q] = ps[i] + ((i >= off) ? ps[i-off] : 0u);
    }
    __syncthreads();
    #pragma unroll
    for (int q = 0; q < 4; q++) ps[tid + q*1024] = v[q];
    __syncthreads();
  }
  #pragma unroll
  for (int q = 0; q < 4; q++){
    int i = tid + q*1024;
    if (i < NCAND && f[q] && ps[i] <= IMTOP){
      int slot = n*IMTOP + (int)ps[i] - 1;
      int so = n*NCAND + i;
      out[slot*4+0] = sbox[so*4+0]; out[slot*4+1] = sbox[so*4+1];
      out[slot*4+2] = sbox[so*4+2]; out[slot*4+3] = sbox[so*4+3];
    }
  }
  u32 kept = ps[NCAND-1]; if (kept > IMTOP) kept = IMTOP;
  for (int j = tid; j < IMTOP; j += 1024){
    int slot = n*IMTOP + j;
    if ((u32)j >= kept){
      out[slot*4+0]=0; out[slot*4+1]=0; out[slot*4+2]=0; out[slot*4+3]=0;
    }
    out[2400 + slot] = (float)n;
    out[3000 + slot] = ((u32)j < kept) ? 1.0f : 0.0f;
  }
}

extern "C" void kernel_launch(void* const* d_in, const int* in_sizes, int n_in,
                              void* d_out, int out_size, void* d_ws, size_t ws_size,
                              hipStream_t stream)
{
  const float* fmap[5]   = {(const float*)d_in[0], (const float*)d_in[2], (const float*)d_in[4],
                            (const float*)d_in[6], (const float*)d_in[8]};
  const float* priors[5] = {(const float*)d_in[1], (const float*)d_in[3], (const float*)d_in[5],
                            (const float*)d_in[7], (const float*)d_in[9]};
  const float* imsz   = (const float*)d_in[10];
  const float* conv_w = (const float*)d_in[11];
  const float* conv_b = (const float*)d_in[12];
  const float* log_w  = (const float*)d_in[13];
  const float* log_b  = (const float*)d_in[14];
  const float* reg_w  = (const float*)d_in[15];
  const float* reg_b  = (const float*)d_in[16];

  char* base = (char*)d_ws;
  float* lg     = (float*)(base + 0);          // 1943928 B
  float* rg     = (float*)(base + 1943928);    // 7775712 B
  float* cscore = (float*)(base + 9719640);
  float* cbox   = (float*)(base + 9743640);
  u32*   cvalid = (u32*)  (base + 9839640);
  float* sbox   = (float*)(base + 9863640);
  float* sob    = (float*)(base + 9959640);
  float* sarea  = (float*)(base + 10055640);
  u32*   svalid = (u32*)  (base + 10079640);
  u32*   rlist  = (u32*)  (base + 10103640);   // 24000 B
  u32*   kflag  = (u32*)  (base + 10127640);   // 24000 B
  u64*   pmask  = (u64*)  (base + 10151648);   // 480000 B
  u16*   wT     = (u16*)  (base + 10631648);   // 2359296 B
  u16*   whB    = (u16*)  (base + 12990944);   // 16384 B
  u16*   zp     = (u16*)  (base + 13007328);   // 16 B zero page
  u16*   xh     = (u16*)  (base + 13007344);   // 82940928 B
  u16*   xl     = (u16*)  (base + 95948272);   // 82940928 B -> 178889200

  int use_dma = (ws_size >= WS_NEED) ? 1 : 0;

  wprep<<<73, 256, 0, stream>>>(conv_w, log_w, reg_w, wT, whB);
  if (use_dma)
    xsplit<<<(NCHUNK + 255)/256, 256, 0, stream>>>(
        fmap[0], fmap[1], fmap[2], fmap[3], fmap[4], xh, xl, zp);

  conv_mfma<<<dim3(1438, NIMG), 256, 0, stream>>>(
      fmap[0], fmap[1], fmap[2], fmap[3], fmap[4],
      xh, xl, zp, wT, whB, conv_b, log_b, reg_b, lg, rg, use_dma);

  topk_decode<<<NLVL*NIMG, 1024, 0, stream>>>(lg, rg,
      priors[0], priors[1], priors[2], priors[3], priors[4],
      imsz, cbox, cscore, cvalid);
  sort_cand<<<NIMG, 1024, 0, stream>>>(cscore, cvalid, cbox, sbox, sob, sarea,
                                       svalid, rlist, kflag);
  nms_mask_l<<<dim3(3, NIMG*NLVL), 256, 0, stream>>>(sob, sarea, svalid, rlist, pmask);
  nms_scan_l<<<NIMG*NLVL, 64, 0, stream>>>(pmask, svalid, rlist, kflag);
  merge_out<<<NIMG, 1024, 0, stream>>>(kflag, sbox, (float*)d_out);
}